// Round 1
// baseline (11617.897 us; speedup 1.0000x reference)
//
#include <hip/hip_runtime.h>
#include <math.h>

#define NN 50000      // nodes
#define NE 1000000    // edges
#define D 64          // hidden
#define FIN 19
#define EHD 50        // edge attr dim
#define NG 128        // graphs
#define NBLK 3

#define PI_OVER_CUT 0.6283185307179586f
#define LN2F 0.6931471805599453f

static __device__ __forceinline__ float sspf(float x) {
  // shifted softplus: log(1+exp(x)) - ln2, numerically stable
  return fmaxf(x, 0.0f) + log1pf(expf(-fabsf(x))) - LN2F;
}
static __device__ __forceinline__ float sigm(float x) {
  return 1.0f / (1.0f + expf(-x));
}

// ---- envelope C[e] = cos(w*pi/5)*0.5+0.5 ; degree count via atomics ----
__global__ __launch_bounds__(256) void k_env(const float* __restrict__ ew,
                                             const int* __restrict__ ei,
                                             float* __restrict__ C,
                                             float* __restrict__ deg) {
  int e = blockIdx.x * 256 + threadIdx.x;
  if (e >= NE) return;
  C[e] = cosf(ew[e] * PI_OVER_CUT) * 0.5f + 0.5f;
  atomicAdd(&deg[ei[NE + e]], 1.0f);
}

__global__ __launch_bounds__(256) void k_deginv(float* __restrict__ deg) {
  int n = blockIdx.x * 256 + threadIdx.x;
  if (n < NN) deg[n] = 1.0f / fmaxf(deg[n], 1.0f);
}

// ---- transpose conv_mlp_w1 (NB,32,EHD) -> (NB,EHD,32) for contiguous s_loads ----
__global__ __launch_bounds__(256) void k_prep(const float* __restrict__ w1,
                                              float* __restrict__ w1t) {
  int i = blockIdx.x * 256 + threadIdx.x;
  if (i >= NBLK * 32 * EHD) return;
  int b = i / (32 * EHD);
  int j = (i / EHD) % 32;
  int k = i % EHD;
  w1t[b * EHD * 32 + k * 32 + j] = w1[i];
}

// ---- graph boundaries via binary search over sorted batch ----
__global__ void k_bounds(const int* __restrict__ batch, int* __restrict__ bounds) {
  int g = threadIdx.x;
  if (g > NG) return;
  int lo = 0, hi = NN;
  while (lo < hi) { int mid = (lo + hi) >> 1; if (batch[mid] < g) lo = mid + 1; else hi = mid; }
  bounds[g] = lo;
}

// ---- lin0: S = leaky_relu(x @ W^T + b). thread = node; weight loads wave-uniform ----
__global__ __launch_bounds__(256) void k_lin0(const float* __restrict__ x,
                                              const float* __restrict__ w,
                                              const float* __restrict__ bias,
                                              float* __restrict__ S) {
  int n = blockIdx.x * 256 + threadIdx.x;
  if (n >= NN) return;
  float xr[FIN];
  #pragma unroll
  for (int k = 0; k < FIN; k++) xr[k] = x[n * FIN + k];
  for (int d = 0; d < D; d++) {
    float a0 = bias[d], a1 = 0.f;
    #pragma unroll
    for (int k = 0; k < FIN - 1; k += 2) {
      a0 += xr[k] * w[d * FIN + k];
      a1 += xr[k + 1] * w[d * FIN + k + 1];
    }
    a0 += xr[FIN - 1] * w[d * FIN + FIN - 1];
    float acc = a0 + a1;
    S[(size_t)n * D + d] = acc > 0.f ? acc : 0.01f * acc;
  }
}

// ---- hx = S @ lin1^T ; also zero agg for the upcoming edge scatter ----
__global__ __launch_bounds__(128) void k_hx(const float* __restrict__ S,
                                            const float* __restrict__ w,
                                            float* __restrict__ hx,
                                            float* __restrict__ agg) {
  int n = blockIdx.x * 128 + threadIdx.x;
  if (n >= NN) return;
  float in_[D];
  const float4* Sv = (const float4*)(S + (size_t)n * D);
  #pragma unroll
  for (int q = 0; q < 16; q++) {
    float4 v = Sv[q];
    in_[4*q] = v.x; in_[4*q+1] = v.y; in_[4*q+2] = v.z; in_[4*q+3] = v.w;
  }
  float4* av = (float4*)(agg + (size_t)n * D);
  #pragma unroll
  for (int q = 0; q < 16; q++) av[q] = make_float4(0.f, 0.f, 0.f, 0.f);
  for (int d = 0; d < D; d++) {
    float a0 = 0, a1 = 0, a2 = 0, a3 = 0;
    #pragma unroll
    for (int k = 0; k < D; k += 4) {
      a0 += in_[k]   * w[d * D + k];
      a1 += in_[k+1] * w[d * D + k + 1];
      a2 += in_[k+2] * w[d * D + k + 2];
      a3 += in_[k+3] * w[d * D + k + 3];
    }
    hx[(size_t)n * D + d] = (a0 + a1) + (a2 + a3);
  }
}

// ---- edge kernel: Wm = (relu(ea@W1^T+b1)@W2^T+b2)*C ; agg[dst] += hx[src]*Wm ----
// thread = edge; all weight indices wave-uniform -> s_load + v_fmac (1 instr/MAC)
__global__ __launch_bounds__(256) void k_edge(const float* __restrict__ ea,
                                              const float* __restrict__ w1t,
                                              const float* __restrict__ b1,
                                              const float* __restrict__ w2,
                                              const float* __restrict__ b2,
                                              const float* __restrict__ C,
                                              const int* __restrict__ ei,
                                              const float* __restrict__ hx,
                                              float* __restrict__ agg) {
  int e = blockIdx.x * 256 + threadIdx.x;
  if (e >= NE) return;
  float t[32];
  #pragma unroll
  for (int j = 0; j < 32; j++) t[j] = b1[j];
  const float* ear = ea + (size_t)e * EHD;
  for (int k = 0; k < EHD; k++) {
    float a = ear[k];
    #pragma unroll
    for (int j = 0; j < 32; j++) t[j] += a * w1t[k * 32 + j];
  }
  #pragma unroll
  for (int j = 0; j < 32; j++) t[j] = fmaxf(t[j], 0.0f);
  float cv = C[e];
  int src = ei[e], dst = ei[NE + e];
  const float* hr = hx + (size_t)src * D;
  float* ar = agg + (size_t)dst * D;
  for (int d = 0; d < D; d++) {
    float a0 = b2[d], a1 = 0, a2 = 0, a3 = 0;
    #pragma unroll
    for (int j = 0; j < 32; j += 4) {
      a0 += t[j]   * w2[d * 32 + j];
      a1 += t[j+1] * w2[d * 32 + j + 1];
      a2 += t[j+2] * w2[d * 32 + j + 2];
      a3 += t[j+3] * w2[d * 32 + j + 3];
    }
    float wm = (a0 + a1) + (a2 + a3);
    atomicAdd(&ar[d], wm * cv * hr[d]);
  }
}

// ---- node kernel: m = ssp(agg/deg @ lin2^T + b)@lin3^T + b ; h = GRU(m, h) ----
// thread = node; LDS slot (stride 65, conflict-free) bounces rows between stages
// so runtime d-loops never index register arrays (scratch trap).
__global__ __launch_bounds__(128) void k_node(const float* __restrict__ agg,
                                              const float* __restrict__ dinv,
                                              const float* __restrict__ w2,
                                              const float* __restrict__ b2,
                                              const float* __restrict__ w3,
                                              const float* __restrict__ b3,
                                              const float* __restrict__ wih,
                                              const float* __restrict__ whh,
                                              const float* __restrict__ bih,
                                              const float* __restrict__ bhh,
                                              float* __restrict__ S) {
  __shared__ float lds[128 * 65];
  int n = blockIdx.x * 128 + threadIdx.x;
  if (n >= NN) return;
  float* slot = lds + threadIdx.x * 65;
  float di = dinv[n];
  float in_[D];
  const float4* av = (const float4*)(agg + (size_t)n * D);
  #pragma unroll
  for (int q = 0; q < 16; q++) {
    float4 v = av[q];
    in_[4*q] = v.x * di; in_[4*q+1] = v.y * di; in_[4*q+2] = v.z * di; in_[4*q+3] = v.w * di;
  }
  // lin2 + ssp
  for (int d = 0; d < D; d++) {
    float a0 = b2[d], a1 = 0, a2 = 0, a3 = 0;
    #pragma unroll
    for (int k = 0; k < D; k += 4) {
      a0 += in_[k]   * w2[d * D + k];
      a1 += in_[k+1] * w2[d * D + k + 1];
      a2 += in_[k+2] * w2[d * D + k + 2];
      a3 += in_[k+3] * w2[d * D + k + 3];
    }
    slot[d] = sspf((a0 + a1) + (a2 + a3));
  }
  #pragma unroll
  for (int k = 0; k < D; k++) in_[k] = slot[k];
  // lin3 -> m
  for (int d = 0; d < D; d++) {
    float a0 = b3[d], a1 = 0, a2 = 0, a3 = 0;
    #pragma unroll
    for (int k = 0; k < D; k += 4) {
      a0 += in_[k]   * w3[d * D + k];
      a1 += in_[k+1] * w3[d * D + k + 1];
      a2 += in_[k+2] * w3[d * D + k + 2];
      a3 += in_[k+3] * w3[d * D + k + 3];
    }
    slot[d] = (a0 + a1) + (a2 + a3);
  }
  float m_[D], h_[D];
  #pragma unroll
  for (int k = 0; k < D; k++) m_[k] = slot[k];
  const float4* hv = (const float4*)(S + (size_t)n * D);
  #pragma unroll
  for (int q = 0; q < 16; q++) {
    float4 v = hv[q];
    h_[4*q] = v.x; h_[4*q+1] = v.y; h_[4*q+2] = v.z; h_[4*q+3] = v.w;
  }
  // GRU: 6 independent FMA chains per d give ILP
  for (int d = 0; d < D; d++) {
    float ir = bih[d], iz = bih[D + d], in2 = bih[2 * D + d];
    float hr = bhh[d], hz = bhh[D + d], hn = bhh[2 * D + d];
    #pragma unroll
    for (int k = 0; k < D; k++) {
      float mm = m_[k], hh = h_[k];
      ir  += mm * wih[d * D + k];
      iz  += mm * wih[(D + d) * D + k];
      in2 += mm * wih[(2 * D + d) * D + k];
      hr  += hh * whh[d * D + k];
      hz  += hh * whh[(D + d) * D + k];
      hn  += hh * whh[(2 * D + d) * D + k];
    }
    float r = sigm(ir + hr), zg = sigm(iz + hz);
    float nn2 = tanhf(in2 + r * hn);
    S[(size_t)n * D + d] = (1.0f - zg) * nn2 + zg * h_[d];
  }
}

// ---- Set2Set LSTM step. 1 wave per graph; thread d owns gate rows d,64+d,128+d,192+d ----
__global__ __launch_bounds__(64) void k_lstm(const float* __restrict__ wih,
                                             const float* __restrict__ whh,
                                             const float* __restrict__ bih,
                                             const float* __restrict__ bhh,
                                             float* __restrict__ qstar,
                                             float* __restrict__ hl,
                                             float* __restrict__ cl) {
  int g = blockIdx.x, d = threadIdx.x;
  const float* qs = qstar + g * 2 * D;  // wave-uniform reads
  const float* hr = hl + g * D;
  float ai = bih[d]         + bhh[d];
  float af = bih[D + d]     + bhh[D + d];
  float ag = bih[2 * D + d] + bhh[2 * D + d];
  float ao = bih[3 * D + d] + bhh[3 * D + d];
  #pragma unroll 8
  for (int k = 0; k < 2 * D; k++) {
    float q = qs[k];
    ai += q * wih[d * 2 * D + k];
    af += q * wih[(D + d) * 2 * D + k];
    ag += q * wih[(2 * D + d) * 2 * D + k];
    ao += q * wih[(3 * D + d) * 2 * D + k];
  }
  #pragma unroll 8
  for (int k = 0; k < D; k++) {
    float h = hr[k];
    ai += h * whh[d * D + k];
    af += h * whh[(D + d) * D + k];
    ag += h * whh[(2 * D + d) * D + k];
    ao += h * whh[(3 * D + d) * D + k];
  }
  // single wave: all reads above retire before the stores below issue
  float c = sigm(af) * cl[g * D + d] + sigm(ai) * tanhf(ag);
  float hn = sigm(ao) * tanhf(c);
  cl[g * D + d] = c;
  hl[g * D + d] = hn;
  qstar[g * 2 * D + d] = hn;  // q half of q_star
}

// ---- Set2Set attention: per-graph softmax over nodes + weighted readout ----
__global__ __launch_bounds__(256) void k_attn(const float* __restrict__ S,
                                              const int* __restrict__ bounds,
                                              float* __restrict__ qstar,
                                              float* __restrict__ ebuf) {
  __shared__ float qv[D];
  __shared__ float red[256];
  int g = blockIdx.x, tid = threadIdx.x;
  int s = bounds[g], en = bounds[g + 1];
  if (tid < D) qv[tid] = qstar[g * 2 * D + tid];
  __syncthreads();
  float lmax = -1e30f;
  for (int n = s + tid; n < en; n += 256) {
    const float4* Sv = (const float4*)(S + (size_t)n * D);
    float a0 = 0, a1 = 0, a2 = 0, a3 = 0;
    #pragma unroll
    for (int q = 0; q < 16; q++) {
      float4 v = Sv[q];
      a0 += v.x * qv[4*q]; a1 += v.y * qv[4*q+1];
      a2 += v.z * qv[4*q+2]; a3 += v.w * qv[4*q+3];
    }
    float e = (a0 + a1) + (a2 + a3);
    ebuf[n] = e;
    lmax = fmaxf(lmax, e);
  }
  red[tid] = lmax; __syncthreads();
  for (int st = 128; st > 0; st >>= 1) {
    if (tid < st) red[tid] = fmaxf(red[tid], red[tid + st]);
    __syncthreads();
  }
  float smax = red[0]; __syncthreads();
  float lsum = 0;
  for (int n = s + tid; n < en; n += 256) {
    float p = expf(ebuf[n] - smax);
    ebuf[n] = p;
    lsum += p;
  }
  red[tid] = lsum; __syncthreads();
  for (int st = 128; st > 0; st >>= 1) {
    if (tid < st) red[tid] += red[tid + st];
    __syncthreads();
  }
  float inv = red[0] > 0.f ? 1.0f / red[0] : 0.0f;
  __syncthreads();
  int grp = tid >> 6, d = tid & 63;
  float acc = 0;
  for (int n = s + grp; n < en; n += 4)
    acc += ebuf[n] * S[(size_t)n * D + d];  // coalesced across d
  red[tid] = acc; __syncthreads();
  if (tid < D)
    qstar[g * 2 * D + D + tid] =
        (red[tid] + red[64 + tid] + red[128 + tid] + red[192 + tid]) * inv;
}

// ---- final: g = relu(q_star@lin1^T+b) ; energy = g@lin2^T+b ; + atom refs ----
__global__ __launch_bounds__(64) void k_final(const float* __restrict__ qstar,
                                              const float* __restrict__ w1,
                                              const float* __restrict__ b1,
                                              const float* __restrict__ w2,
                                              const float* __restrict__ b2,
                                              const int* __restrict__ z,
                                              const float* __restrict__ eref,
                                              const float* __restrict__ aref,
                                              const int* __restrict__ bounds,
                                              float* __restrict__ outp) {
  __shared__ float red[D];
  int g = blockIdx.x, d = threadIdx.x;
  const float* qs = qstar + g * 2 * D;  // wave-uniform
  float a0 = 0, a1 = 0, a2 = 0, a3 = 0;
  #pragma unroll
  for (int k = 0; k < 2 * D; k += 4) {
    a0 += qs[k]   * w1[d * 2 * D + k];
    a1 += qs[k+1] * w1[d * 2 * D + k + 1];
    a2 += qs[k+2] * w1[d * 2 * D + k + 2];
    a3 += qs[k+3] * w1[d * 2 * D + k + 3];
  }
  float gv = fmaxf((a0 + a1) + (a2 + a3) + b1[d], 0.0f);
  red[d] = gv * w2[d];
  __syncthreads();
  for (int st = 32; st > 0; st >>= 1) {
    if (d < st) red[d] += red[d + st];
    __syncthreads();
  }
  float energy = red[0] + b2[0];
  __syncthreads();
  int s = bounds[g], en = bounds[g + 1];
  float racc = 0;
  for (int n = s + d; n < en; n += 64) {
    int zz = z[n];
    racc += eref[zz] + aref[zz];
  }
  red[d] = racc; __syncthreads();
  for (int st = 32; st > 0; st >>= 1) {
    if (d < st) red[d] += red[d + st];
    __syncthreads();
  }
  if (d == 0) outp[g] = energy + red[0];
}

extern "C" void kernel_launch(void* const* d_in, const int* in_sizes, int n_in,
                              void* d_out, int out_size, void* d_ws, size_t ws_size,
                              hipStream_t stream) {
  const float* x      = (const float*)d_in[0];
  const int*   ei     = (const int*)d_in[1];
  const float* ew     = (const float*)d_in[2];
  const float* ea     = (const float*)d_in[3];
  const int*   z      = (const int*)d_in[4];
  const int*   batch  = (const int*)d_in[5];
  const float* lin0_w = (const float*)d_in[6];
  const float* lin0_b = (const float*)d_in[7];
  const float* cw1    = (const float*)d_in[8];
  const float* cb1    = (const float*)d_in[9];
  const float* cw2    = (const float*)d_in[10];
  const float* cb2    = (const float*)d_in[11];
  const float* cl1w   = (const float*)d_in[12];
  const float* cl2w   = (const float*)d_in[13];
  const float* cl2b   = (const float*)d_in[14];
  const float* cl3w   = (const float*)d_in[15];
  const float* cl3b   = (const float*)d_in[16];
  const float* gwih   = (const float*)d_in[17];
  const float* gwhh   = (const float*)d_in[18];
  const float* gbih   = (const float*)d_in[19];
  const float* gbhh   = (const float*)d_in[20];
  const float* lwih   = (const float*)d_in[21];
  const float* lwhh   = (const float*)d_in[22];
  const float* lbih   = (const float*)d_in[23];
  const float* lbhh   = (const float*)d_in[24];
  const float* l1w    = (const float*)d_in[25];
  const float* l1b    = (const float*)d_in[26];
  const float* l2w    = (const float*)d_in[27];
  const float* l2b    = (const float*)d_in[28];
  const float* aref   = (const float*)d_in[29];
  const float* eref   = (const float*)d_in[30];
  float* outp = (float*)d_out;

  float* f = (float*)d_ws;
  float* S     = f;                       // N*D
  float* hx    = f + 3200000;             // N*D
  float* agg   = f + 6400000;             // N*D
  float* Cb    = f + 9600000;             // E
  float* ebuf  = f + 10600000;            // N
  float* deg   = f + 10656000;            // N
  float* qstar = f + 10707200;            // NG*2D
  float* hl    = qstar + NG * 2 * D;      // NG*D
  float* cls   = hl + NG * D;             // NG*D
  float* w1t   = cls + NG * D;            // NB*EHD*32
  int* bounds  = (int*)(w1t + NBLK * 32 * EHD);  // NG+1

  hipMemsetAsync(deg, 0, NN * sizeof(float), stream);
  hipMemsetAsync(qstar, 0, (NG * 2 * D + 2 * NG * D) * sizeof(float), stream);

  k_prep<<<19, 256, 0, stream>>>(cw1, w1t);
  k_env<<<(NE + 255) / 256, 256, 0, stream>>>(ew, ei, Cb, deg);
  k_deginv<<<(NN + 255) / 256, 256, 0, stream>>>(deg);
  k_lin0<<<(NN + 255) / 256, 256, 0, stream>>>(x, lin0_w, lin0_b, S);
  k_bounds<<<1, 192, 0, stream>>>(batch, bounds);

  for (int b = 0; b < NBLK; b++) {
    k_hx<<<(NN + 127) / 128, 128, 0, stream>>>(S, cl1w + b * D * D, hx, agg);
    k_edge<<<(NE + 255) / 256, 256, 0, stream>>>(
        ea, w1t + b * EHD * 32, cb1 + b * 32, cw2 + b * D * 32, cb2 + b * D,
        Cb, ei, hx, agg);
    k_node<<<(NN + 127) / 128, 128, 0, stream>>>(
        agg, deg, cl2w + b * D * D, cl2b + b * D, cl3w + b * D * D, cl3b + b * D,
        gwih, gwhh, gbih, gbhh, S);
  }

  for (int it = 0; it < 3; it++) {
    k_lstm<<<NG, 64, 0, stream>>>(lwih, lwhh, lbih, lbhh, qstar, hl, cls);
    k_attn<<<NG, 256, 0, stream>>>(S, bounds, qstar, ebuf);
  }

  k_final<<<NG, 64, 0, stream>>>(qstar, l1w, l1b, l2w, l2b, z, eref, aref,
                                 bounds, outp);
}

// Round 2
// 3516.206 us; speedup vs baseline: 3.3041x; 3.3041x over previous
//
#include <hip/hip_runtime.h>
#include <math.h>

#define NN 50000      // nodes
#define NE 1000000    // edges
#define D 64          // hidden
#define FIN 19
#define EHD 50        // edge attr dim
#define NG 128        // graphs
#define NBLK 3

#define PI_OVER_CUT 0.6283185307179586f
#define LN2F 0.6931471805599453f

// ---- workspace layout (float offsets) ----
#define OFF_S     0L
#define OFF_HX    3200000L
#define OFF_AGG   6400000L
#define OFF_CB    9600000L
#define OFF_DINV  10600000L
#define OFF_EBUF  10665536L            // aliased: degi/cursor (int) during setup
#define OFF_QSTAR 10731072L
#define OFF_HL    (OFF_QSTAR + 16384L)
#define OFF_CL    (OFF_HL + 8192L)
#define OFF_W1T   (OFF_CL + 8192L)
#define OFF_BNDS  (OFF_W1T + 8192L)    // 10772032, 448 floats of room
#define OFF_ES    10772480L            // E ints
#define OFF_START 11772480L            // N+1 ints
#define OFF_MSG   11838464L            // chunk msg buffer, capE*64 floats

static __device__ __forceinline__ float sspf(float x) {
  return fmaxf(x, 0.0f) + log1pf(expf(-fabsf(x))) - LN2F;
}
static __device__ __forceinline__ float sigm(float x) {
  return 1.0f / (1.0f + expf(-x));
}

// ---- envelope + int degree count ----
__global__ __launch_bounds__(256) void k_env(const float* __restrict__ ew,
                                             const int* __restrict__ ei,
                                             float* __restrict__ C,
                                             int* __restrict__ degi) {
  int e = blockIdx.x * 256 + threadIdx.x;
  if (e >= NE) return;
  C[e] = cosf(ew[e] * PI_OVER_CUT) * 0.5f + 0.5f;
  atomicAdd(&degi[ei[NE + e]], 1);
}

// ---- single-block prefix scan: degi -> start, dinv; zeroes degi (becomes cursor) ----
__global__ __launch_bounds__(1024) void k_scan(int* __restrict__ degi,
                                               int* __restrict__ start,
                                               float* __restrict__ dinv) {
  __shared__ int part[1024];
  int t = threadIdx.x;
  const int CH = (NN + 1023) / 1024;
  int lo = t * CH, hi = lo + CH;
  if (hi > NN) hi = NN;
  int s = 0;
  for (int i = lo; i < hi; i++) s += degi[i];
  part[t] = s;
  __syncthreads();
  for (int off = 1; off < 1024; off <<= 1) {
    int v = (t >= off) ? part[t - off] : 0;
    __syncthreads();
    part[t] += v;
    __syncthreads();
  }
  int run = (t == 0) ? 0 : part[t - 1];
  for (int i = lo; i < hi; i++) {
    int d = degi[i];
    degi[i] = 0;                       // becomes cursor for k_slot
    start[i] = run;
    dinv[i] = 1.0f / fmaxf((float)d, 1.0f);
    run += d;
  }
  if (t == 1023) start[NN] = run;
}

// ---- fallback dinv (atomic path) ----
__global__ __launch_bounds__(256) void k_dinv(const int* __restrict__ degi,
                                              float* __restrict__ dinv) {
  int n = blockIdx.x * 256 + threadIdx.x;
  if (n < NN) dinv[n] = 1.0f / fmaxf((float)degi[n], 1.0f);
}

// ---- CSR slot assignment: es[slot] = edge id (order within node arbitrary) ----
__global__ __launch_bounds__(256) void k_slot(const int* __restrict__ ei,
                                              const int* __restrict__ start,
                                              int* __restrict__ cursor,
                                              int* __restrict__ es) {
  int e = blockIdx.x * 256 + threadIdx.x;
  if (e >= NE) return;
  int dst = ei[NE + e];
  int ofs = atomicAdd(&cursor[dst], 1);
  es[start[dst] + ofs] = e;
}

// ---- transpose conv_mlp_w1 (NB,32,EHD) -> (NB,EHD,32) ----
__global__ __launch_bounds__(256) void k_prep(const float* __restrict__ w1,
                                              float* __restrict__ w1t) {
  int i = blockIdx.x * 256 + threadIdx.x;
  if (i >= NBLK * 32 * EHD) return;
  int b = i / (32 * EHD);
  int j = (i / EHD) % 32;
  int k = i % EHD;
  w1t[b * EHD * 32 + k * 32 + j] = w1[i];
}

// ---- graph boundaries via binary search over sorted batch ----
__global__ void k_bounds(const int* __restrict__ batch, int* __restrict__ bounds) {
  int g = threadIdx.x;
  if (g > NG) return;
  int lo = 0, hi = NN;
  while (lo < hi) { int mid = (lo + hi) >> 1; if (batch[mid] < g) lo = mid + 1; else hi = mid; }
  bounds[g] = lo;
}

// ---- lin0: S = leaky_relu(x @ W^T + b) ----
__global__ __launch_bounds__(256) void k_lin0(const float* __restrict__ x,
                                              const float* __restrict__ w,
                                              const float* __restrict__ bias,
                                              float* __restrict__ S) {
  int n = blockIdx.x * 256 + threadIdx.x;
  if (n >= NN) return;
  float xr[FIN];
  #pragma unroll
  for (int k = 0; k < FIN; k++) xr[k] = x[n * FIN + k];
  for (int d = 0; d < D; d++) {
    float a0 = bias[d], a1 = 0.f;
    #pragma unroll
    for (int k = 0; k < FIN - 1; k += 2) {
      a0 += xr[k] * w[d * FIN + k];
      a1 += xr[k + 1] * w[d * FIN + k + 1];
    }
    a0 += xr[FIN - 1] * w[d * FIN + FIN - 1];
    float acc = a0 + a1;
    S[(size_t)n * D + d] = acc > 0.f ? acc : 0.01f * acc;
  }
}

// ---- hx = S @ lin1^T ; optionally zero agg (atomic-fallback path only) ----
__global__ __launch_bounds__(128) void k_hx(const float* __restrict__ S,
                                            const float* __restrict__ w,
                                            float* __restrict__ hx,
                                            float* __restrict__ agg,
                                            int zero_agg) {
  int n = blockIdx.x * 128 + threadIdx.x;
  if (n >= NN) return;
  float in_[D];
  const float4* Sv = (const float4*)(S + (size_t)n * D);
  #pragma unroll
  for (int q = 0; q < 16; q++) {
    float4 v = Sv[q];
    in_[4*q] = v.x; in_[4*q+1] = v.y; in_[4*q+2] = v.z; in_[4*q+3] = v.w;
  }
  if (zero_agg) {
    float4* av = (float4*)(agg + (size_t)n * D);
    #pragma unroll
    for (int q = 0; q < 16; q++) av[q] = make_float4(0.f, 0.f, 0.f, 0.f);
  }
  for (int d = 0; d < D; d++) {
    float a0 = 0, a1 = 0, a2 = 0, a3 = 0;
    #pragma unroll
    for (int k = 0; k < D; k += 4) {
      a0 += in_[k]   * w[d * D + k];
      a1 += in_[k+1] * w[d * D + k + 1];
      a2 += in_[k+2] * w[d * D + k + 2];
      a3 += in_[k+3] * w[d * D + k + 3];
    }
    hx[(size_t)n * D + d] = (a0 + a1) + (a2 + a3);
  }
}

// ---- CSR edge kernel: thread = slot; MLP + plain store of msg row ----
__global__ __launch_bounds__(256) void k_edgeg(const float* __restrict__ ea,
                                               const float* __restrict__ w1t,
                                               const float* __restrict__ b1,
                                               const float* __restrict__ w2,
                                               const float* __restrict__ b2,
                                               const float* __restrict__ C,
                                               const int* __restrict__ ei,
                                               const int* __restrict__ es,
                                               const int* __restrict__ start,
                                               const float* __restrict__ hx,
                                               float* __restrict__ msgc,
                                               int n0, int n1, int cap) {
  int c0 = start[n0], c1 = start[n1];
  int s = c0 + blockIdx.x * 256 + threadIdx.x;
  if (s >= c1 || (s - c0) >= cap) return;
  int e = es[s];
  float t[32];
  #pragma unroll
  for (int j = 0; j < 32; j++) t[j] = b1[j];
  const float2* ea2 = (const float2*)(ea + (size_t)e * EHD);
  for (int k2 = 0; k2 < EHD / 2; k2++) {
    float2 v = ea2[k2];
    #pragma unroll
    for (int j = 0; j < 32; j++) t[j] += v.x * w1t[(2 * k2) * 32 + j];
    #pragma unroll
    for (int j = 0; j < 32; j++) t[j] += v.y * w1t[(2 * k2 + 1) * 32 + j];
  }
  #pragma unroll
  for (int j = 0; j < 32; j++) t[j] = fmaxf(t[j], 0.0f);
  float cv = C[e];
  int src = ei[e];
  const float4* hr4 = (const float4*)(hx + (size_t)src * D);
  float4* mr4 = (float4*)(msgc + (size_t)(s - c0) * D);
  for (int dq = 0; dq < 16; dq++) {
    float4 hv = hr4[dq];
    float o[4];
    #pragma unroll
    for (int u = 0; u < 4; u++) {
      int d = dq * 4 + u;
      float a0 = b2[d], a1 = 0, a2 = 0, a3 = 0;
      #pragma unroll
      for (int j = 0; j < 32; j += 4) {
        a0 += t[j]   * w2[d * 32 + j];
        a1 += t[j+1] * w2[d * 32 + j + 1];
        a2 += t[j+2] * w2[d * 32 + j + 2];
        a3 += t[j+3] * w2[d * 32 + j + 3];
      }
      o[u] = ((a0 + a1) + (a2 + a3)) * cv;
    }
    mr4[dq] = make_float4(o[0] * hv.x, o[1] * hv.y, o[2] * hv.z, o[3] * hv.w);
  }
}

// ---- gather: wave per node, lane = d; sum contiguous slot range ----
__global__ __launch_bounds__(256) void k_agg(const float* __restrict__ msgc,
                                             const int* __restrict__ start,
                                             float* __restrict__ agg,
                                             int n0, int n1, int cap) {
  int n = n0 + blockIdx.x * 4 + (threadIdx.x >> 6);
  if (n >= n1) return;
  int lane = threadIdx.x & 63;
  int c0 = start[n0];
  int s0 = start[n], s1 = start[n + 1];
  float acc = 0;
  for (int s = s0; s < s1; s++) {
    int off = s - c0;
    if (off < cap) acc += msgc[(size_t)off * D + lane];
  }
  agg[(size_t)n * D + lane] = acc;
}

// ---- fallback: atomic scatter edge kernel (round-1) ----
__global__ __launch_bounds__(256) void k_edge(const float* __restrict__ ea,
                                              const float* __restrict__ w1t,
                                              const float* __restrict__ b1,
                                              const float* __restrict__ w2,
                                              const float* __restrict__ b2,
                                              const float* __restrict__ C,
                                              const int* __restrict__ ei,
                                              const float* __restrict__ hx,
                                              float* __restrict__ agg) {
  int e = blockIdx.x * 256 + threadIdx.x;
  if (e >= NE) return;
  float t[32];
  #pragma unroll
  for (int j = 0; j < 32; j++) t[j] = b1[j];
  const float* ear = ea + (size_t)e * EHD;
  for (int k = 0; k < EHD; k++) {
    float a = ear[k];
    #pragma unroll
    for (int j = 0; j < 32; j++) t[j] += a * w1t[k * 32 + j];
  }
  #pragma unroll
  for (int j = 0; j < 32; j++) t[j] = fmaxf(t[j], 0.0f);
  float cv = C[e];
  int src = ei[e], dst = ei[NE + e];
  const float* hr = hx + (size_t)src * D;
  float* ar = agg + (size_t)dst * D;
  for (int d = 0; d < D; d++) {
    float a0 = b2[d], a1 = 0, a2 = 0, a3 = 0;
    #pragma unroll
    for (int j = 0; j < 32; j += 4) {
      a0 += t[j]   * w2[d * 32 + j];
      a1 += t[j+1] * w2[d * 32 + j + 1];
      a2 += t[j+2] * w2[d * 32 + j + 2];
      a3 += t[j+3] * w2[d * 32 + j + 3];
    }
    float wm = (a0 + a1) + (a2 + a3);
    atomicAdd(&ar[d], wm * cv * hr[d]);
  }
}

// ---- node kernel: m = ssp(agg*dinv @ lin2^T + b)@lin3^T + b ; h = GRU(m, h) ----
__global__ __launch_bounds__(128) void k_node(const float* __restrict__ agg,
                                              const float* __restrict__ dinv,
                                              const float* __restrict__ w2,
                                              const float* __restrict__ b2,
                                              const float* __restrict__ w3,
                                              const float* __restrict__ b3,
                                              const float* __restrict__ wih,
                                              const float* __restrict__ whh,
                                              const float* __restrict__ bih,
                                              const float* __restrict__ bhh,
                                              float* __restrict__ S) {
  __shared__ float lds[128 * 65];
  int n = blockIdx.x * 128 + threadIdx.x;
  if (n >= NN) return;
  float* slot = lds + threadIdx.x * 65;
  float di = dinv[n];
  float in_[D];
  const float4* av = (const float4*)(agg + (size_t)n * D);
  #pragma unroll
  for (int q = 0; q < 16; q++) {
    float4 v = av[q];
    in_[4*q] = v.x * di; in_[4*q+1] = v.y * di; in_[4*q+2] = v.z * di; in_[4*q+3] = v.w * di;
  }
  for (int d = 0; d < D; d++) {
    float a0 = b2[d], a1 = 0, a2 = 0, a3 = 0;
    #pragma unroll
    for (int k = 0; k < D; k += 4) {
      a0 += in_[k]   * w2[d * D + k];
      a1 += in_[k+1] * w2[d * D + k + 1];
      a2 += in_[k+2] * w2[d * D + k + 2];
      a3 += in_[k+3] * w2[d * D + k + 3];
    }
    slot[d] = sspf((a0 + a1) + (a2 + a3));
  }
  #pragma unroll
  for (int k = 0; k < D; k++) in_[k] = slot[k];
  for (int d = 0; d < D; d++) {
    float a0 = b3[d], a1 = 0, a2 = 0, a3 = 0;
    #pragma unroll
    for (int k = 0; k < D; k += 4) {
      a0 += in_[k]   * w3[d * D + k];
      a1 += in_[k+1] * w3[d * D + k + 1];
      a2 += in_[k+2] * w3[d * D + k + 2];
      a3 += in_[k+3] * w3[d * D + k + 3];
    }
    slot[d] = (a0 + a1) + (a2 + a3);
  }
  float m_[D], h_[D];
  #pragma unroll
  for (int k = 0; k < D; k++) m_[k] = slot[k];
  const float4* hv = (const float4*)(S + (size_t)n * D);
  #pragma unroll
  for (int q = 0; q < 16; q++) {
    float4 v = hv[q];
    h_[4*q] = v.x; h_[4*q+1] = v.y; h_[4*q+2] = v.z; h_[4*q+3] = v.w;
  }
  for (int d = 0; d < D; d++) {
    float ir = bih[d], iz = bih[D + d], in2 = bih[2 * D + d];
    float hr = bhh[d], hz = bhh[D + d], hn = bhh[2 * D + d];
    #pragma unroll
    for (int k = 0; k < D; k++) {
      float mm = m_[k], hh = h_[k];
      ir  += mm * wih[d * D + k];
      iz  += mm * wih[(D + d) * D + k];
      in2 += mm * wih[(2 * D + d) * D + k];
      hr  += hh * whh[d * D + k];
      hz  += hh * whh[(D + d) * D + k];
      hn  += hh * whh[(2 * D + d) * D + k];
    }
    float r = sigm(ir + hr), zg = sigm(iz + hz);
    float nn2 = tanhf(in2 + r * hn);
    S[(size_t)n * D + d] = (1.0f - zg) * nn2 + zg * h_[d];
  }
}

// ---- Set2Set LSTM step ----
__global__ __launch_bounds__(64) void k_lstm(const float* __restrict__ wih,
                                             const float* __restrict__ whh,
                                             const float* __restrict__ bih,
                                             const float* __restrict__ bhh,
                                             float* __restrict__ qstar,
                                             float* __restrict__ hl,
                                             float* __restrict__ cl) {
  int g = blockIdx.x, d = threadIdx.x;
  const float* qs = qstar + g * 2 * D;
  const float* hr = hl + g * D;
  float ai = bih[d]         + bhh[d];
  float af = bih[D + d]     + bhh[D + d];
  float ag = bih[2 * D + d] + bhh[2 * D + d];
  float ao = bih[3 * D + d] + bhh[3 * D + d];
  #pragma unroll 8
  for (int k = 0; k < 2 * D; k++) {
    float q = qs[k];
    ai += q * wih[d * 2 * D + k];
    af += q * wih[(D + d) * 2 * D + k];
    ag += q * wih[(2 * D + d) * 2 * D + k];
    ao += q * wih[(3 * D + d) * 2 * D + k];
  }
  #pragma unroll 8
  for (int k = 0; k < D; k++) {
    float h = hr[k];
    ai += h * whh[d * D + k];
    af += h * whh[(D + d) * D + k];
    ag += h * whh[(2 * D + d) * D + k];
    ao += h * whh[(3 * D + d) * D + k];
  }
  float c = sigm(af) * cl[g * D + d] + sigm(ai) * tanhf(ag);
  float hn = sigm(ao) * tanhf(c);
  cl[g * D + d] = c;
  hl[g * D + d] = hn;
  qstar[g * 2 * D + d] = hn;
}

// ---- Set2Set attention ----
__global__ __launch_bounds__(256) void k_attn(const float* __restrict__ S,
                                              const int* __restrict__ bounds,
                                              float* __restrict__ qstar,
                                              float* __restrict__ ebuf) {
  __shared__ float qv[D];
  __shared__ float red[256];
  int g = blockIdx.x, tid = threadIdx.x;
  int s = bounds[g], en = bounds[g + 1];
  if (tid < D) qv[tid] = qstar[g * 2 * D + tid];
  __syncthreads();
  float lmax = -1e30f;
  for (int n = s + tid; n < en; n += 256) {
    const float4* Sv = (const float4*)(S + (size_t)n * D);
    float a0 = 0, a1 = 0, a2 = 0, a3 = 0;
    #pragma unroll
    for (int q = 0; q < 16; q++) {
      float4 v = Sv[q];
      a0 += v.x * qv[4*q]; a1 += v.y * qv[4*q+1];
      a2 += v.z * qv[4*q+2]; a3 += v.w * qv[4*q+3];
    }
    float e = (a0 + a1) + (a2 + a3);
    ebuf[n] = e;
    lmax = fmaxf(lmax, e);
  }
  red[tid] = lmax; __syncthreads();
  for (int st = 128; st > 0; st >>= 1) {
    if (tid < st) red[tid] = fmaxf(red[tid], red[tid + st]);
    __syncthreads();
  }
  float smax = red[0]; __syncthreads();
  float lsum = 0;
  for (int n = s + tid; n < en; n += 256) {
    float p = expf(ebuf[n] - smax);
    ebuf[n] = p;
    lsum += p;
  }
  red[tid] = lsum; __syncthreads();
  for (int st = 128; st > 0; st >>= 1) {
    if (tid < st) red[tid] += red[tid + st];
    __syncthreads();
  }
  float inv = red[0] > 0.f ? 1.0f / red[0] : 0.0f;
  __syncthreads();
  int grp = tid >> 6, d = tid & 63;
  float acc = 0;
  for (int n = s + grp; n < en; n += 4)
    acc += ebuf[n] * S[(size_t)n * D + d];
  red[tid] = acc; __syncthreads();
  if (tid < D)
    qstar[g * 2 * D + D + tid] =
        (red[tid] + red[64 + tid] + red[128 + tid] + red[192 + tid]) * inv;
}

// ---- final head ----
__global__ __launch_bounds__(64) void k_final(const float* __restrict__ qstar,
                                              const float* __restrict__ w1,
                                              const float* __restrict__ b1,
                                              const float* __restrict__ w2,
                                              const float* __restrict__ b2,
                                              const int* __restrict__ z,
                                              const float* __restrict__ eref,
                                              const float* __restrict__ aref,
                                              const int* __restrict__ bounds,
                                              float* __restrict__ outp) {
  __shared__ float red[D];
  int g = blockIdx.x, d = threadIdx.x;
  const float* qs = qstar + g * 2 * D;
  float a0 = 0, a1 = 0, a2 = 0, a3 = 0;
  #pragma unroll
  for (int k = 0; k < 2 * D; k += 4) {
    a0 += qs[k]   * w1[d * 2 * D + k];
    a1 += qs[k+1] * w1[d * 2 * D + k + 1];
    a2 += qs[k+2] * w1[d * 2 * D + k + 2];
    a3 += qs[k+3] * w1[d * 2 * D + k + 3];
  }
  float gv = fmaxf((a0 + a1) + (a2 + a3) + b1[d], 0.0f);
  red[d] = gv * w2[d];
  __syncthreads();
  for (int st = 32; st > 0; st >>= 1) {
    if (d < st) red[d] += red[d + st];
    __syncthreads();
  }
  float energy = red[0] + b2[0];
  __syncthreads();
  int s = bounds[g], en = bounds[g + 1];
  float racc = 0;
  for (int n = s + d; n < en; n += 64) {
    int zz = z[n];
    racc += eref[zz] + aref[zz];
  }
  red[d] = racc; __syncthreads();
  for (int st = 32; st > 0; st >>= 1) {
    if (d < st) red[d] += red[d + st];
    __syncthreads();
  }
  if (d == 0) outp[g] = energy + red[0];
}

extern "C" void kernel_launch(void* const* d_in, const int* in_sizes, int n_in,
                              void* d_out, int out_size, void* d_ws, size_t ws_size,
                              hipStream_t stream) {
  const float* x      = (const float*)d_in[0];
  const int*   ei     = (const int*)d_in[1];
  const float* ew     = (const float*)d_in[2];
  const float* ea     = (const float*)d_in[3];
  const int*   z      = (const int*)d_in[4];
  const int*   batch  = (const int*)d_in[5];
  const float* lin0_w = (const float*)d_in[6];
  const float* lin0_b = (const float*)d_in[7];
  const float* cw1    = (const float*)d_in[8];
  const float* cb1    = (const float*)d_in[9];
  const float* cw2    = (const float*)d_in[10];
  const float* cb2    = (const float*)d_in[11];
  const float* cl1w   = (const float*)d_in[12];
  const float* cl2w   = (const float*)d_in[13];
  const float* cl2b   = (const float*)d_in[14];
  const float* cl3w   = (const float*)d_in[15];
  const float* cl3b   = (const float*)d_in[16];
  const float* gwih   = (const float*)d_in[17];
  const float* gwhh   = (const float*)d_in[18];
  const float* gbih   = (const float*)d_in[19];
  const float* gbhh   = (const float*)d_in[20];
  const float* lwih   = (const float*)d_in[21];
  const float* lwhh   = (const float*)d_in[22];
  const float* lbih   = (const float*)d_in[23];
  const float* lbhh   = (const float*)d_in[24];
  const float* l1w    = (const float*)d_in[25];
  const float* l1b    = (const float*)d_in[26];
  const float* l2w    = (const float*)d_in[27];
  const float* l2b    = (const float*)d_in[28];
  const float* aref   = (const float*)d_in[29];
  const float* eref   = (const float*)d_in[30];
  float* outp = (float*)d_out;

  float* f = (float*)d_ws;
  float* S     = f + OFF_S;
  float* hx    = f + OFF_HX;
  float* agg   = f + OFF_AGG;
  float* Cb    = f + OFF_CB;
  float* dinv  = f + OFF_DINV;
  float* ebuf  = f + OFF_EBUF;
  int*   degi  = (int*)(f + OFF_EBUF);   // aliased with ebuf (setup vs readout)
  float* qstar = f + OFF_QSTAR;
  float* hl    = f + OFF_HL;
  float* cls   = f + OFF_CL;
  float* w1t   = f + OFF_W1T;
  int*   bounds= (int*)(f + OFF_BNDS);
  int*   es    = (int*)(f + OFF_ES);
  int*   startA= (int*)(f + OFF_START);
  float* msgc  = f + OFF_MSG;

  // choose chunk count from available workspace (deterministic: ws_size is fixed)
  long wsFloats = (long)(ws_size / 4);
  long capE = (wsFloats - OFF_MSG) / D;
  int NCH = 0;
  long capChunk = 0;
  for (int c = 8; c <= 64; c++) {          // c>=8 keeps chunk msg <= ~43MB (L3-resident)
    long nodesPer = (NN + c - 1) / c;
    long need = ((long)NE * nodesPer / NN) * 13 / 10 + 4096;
    if (need <= capE) { NCH = c; capChunk = need; break; }
  }

  hipMemsetAsync(degi, 0, NN * sizeof(int), stream);
  hipMemsetAsync(qstar, 0, (NG * 2 * D + 2 * NG * D) * sizeof(float), stream);

  k_prep<<<19, 256, 0, stream>>>(cw1, w1t);
  k_env<<<(NE + 255) / 256, 256, 0, stream>>>(ew, ei, Cb, degi);
  if (NCH) {
    k_scan<<<1, 1024, 0, stream>>>(degi, startA, dinv);   // also zeroes degi -> cursor
    k_slot<<<(NE + 255) / 256, 256, 0, stream>>>(ei, startA, degi, es);
  } else {
    k_dinv<<<(NN + 255) / 256, 256, 0, stream>>>(degi, dinv);
  }
  k_lin0<<<(NN + 255) / 256, 256, 0, stream>>>(x, lin0_w, lin0_b, S);
  k_bounds<<<1, 192, 0, stream>>>(batch, bounds);

  for (int b = 0; b < NBLK; b++) {
    k_hx<<<(NN + 127) / 128, 128, 0, stream>>>(S, cl1w + b * D * D, hx, agg,
                                               NCH ? 0 : 1);
    if (NCH) {
      int nodesPer = (NN + NCH - 1) / NCH;
      for (int c = 0; c < NCH; c++) {
        int n0 = c * nodesPer;
        int n1 = n0 + nodesPer; if (n1 > NN) n1 = NN;
        if (n0 >= n1) break;
        k_edgeg<<<(int)((capChunk + 255) / 256), 256, 0, stream>>>(
            ea, w1t + b * EHD * 32, cb1 + b * 32, cw2 + b * D * 32, cb2 + b * D,
            Cb, ei, es, startA, hx, msgc, n0, n1, (int)capChunk);
        k_agg<<<(n1 - n0 + 3) / 4, 256, 0, stream>>>(msgc, startA, agg, n0, n1,
                                                     (int)capChunk);
      }
    } else {
      k_edge<<<(NE + 255) / 256, 256, 0, stream>>>(
          ea, w1t + b * EHD * 32, cb1 + b * 32, cw2 + b * D * 32, cb2 + b * D,
          Cb, ei, hx, agg);
    }
    k_node<<<(NN + 127) / 128, 128, 0, stream>>>(
        agg, dinv, cl2w + b * D * D, cl2b + b * D, cl3w + b * D * D, cl3b + b * D,
        gwih, gwhh, gbih, gbhh, S);
  }

  for (int it = 0; it < 3; it++) {
    k_lstm<<<NG, 64, 0, stream>>>(lwih, lwhh, lbih, lbhh, qstar, hl, cls);
    k_attn<<<NG, 256, 0, stream>>>(S, bounds, qstar, ebuf);
  }

  k_final<<<NG, 64, 0, stream>>>(qstar, l1w, l1b, l2w, l2b, z, eref, aref,
                                 bounds, outp);
}

// Round 3
// 2051.107 us; speedup vs baseline: 5.6642x; 1.7143x over previous
//
#include <hip/hip_runtime.h>
#include <math.h>

#define NN 50000      // nodes
#define NE 1000000    // edges
#define D 64          // hidden
#define FIN 19
#define EHD 50        // edge attr dim
#define NG 128        // graphs
#define NBLK 3

#define PI_OVER_CUT 0.6283185307179586f
#define LN2F 0.6931471805599453f

static __device__ __forceinline__ float sspf(float x) {
  return fmaxf(x, 0.0f) + log1pf(expf(-fabsf(x))) - LN2F;
}
static __device__ __forceinline__ float sigm(float x) {
  return 1.0f / (1.0f + expf(-x));
}

// ---- envelope + int degree count ----
__global__ __launch_bounds__(256) void k_env(const float* __restrict__ ew,
                                             const int* __restrict__ ei,
                                             float* __restrict__ C,
                                             int* __restrict__ degi) {
  int e = blockIdx.x * 256 + threadIdx.x;
  if (e >= NE) return;
  C[e] = cosf(ew[e] * PI_OVER_CUT) * 0.5f + 0.5f;
  atomicAdd(&degi[ei[NE + e]], 1);
}

// ---- single-block prefix scan: degi -> start, dinv; zeroes degi (becomes cursor) ----
__global__ __launch_bounds__(1024) void k_scan(int* __restrict__ degi,
                                               int* __restrict__ start,
                                               float* __restrict__ dinv) {
  __shared__ int part[1024];
  int t = threadIdx.x;
  const int CH = (NN + 1023) / 1024;
  int lo = t * CH, hi = lo + CH;
  if (hi > NN) hi = NN;
  int s = 0;
  for (int i = lo; i < hi; i++) s += degi[i];
  part[t] = s;
  __syncthreads();
  for (int off = 1; off < 1024; off <<= 1) {
    int v = (t >= off) ? part[t - off] : 0;
    __syncthreads();
    part[t] += v;
    __syncthreads();
  }
  int run = (t == 0) ? 0 : part[t - 1];
  for (int i = lo; i < hi; i++) {
    int d = degi[i];
    degi[i] = 0;
    start[i] = run;
    dinv[i] = 1.0f / fmaxf((float)d, 1.0f);
    run += d;
  }
  if (t == 1023) start[NN] = run;
}

// ---- fallback dinv (atomic path) ----
__global__ __launch_bounds__(256) void k_dinv(const int* __restrict__ degi,
                                              float* __restrict__ dinv) {
  int n = blockIdx.x * 256 + threadIdx.x;
  if (n < NN) dinv[n] = 1.0f / fmaxf((float)degi[n], 1.0f);
}

// ---- CSR slot assignment + permuted src / envelope ----
__global__ __launch_bounds__(256) void k_slot2(const int* __restrict__ ei,
                                               const int* __restrict__ start,
                                               int* __restrict__ cursor,
                                               int* __restrict__ es,
                                               int* __restrict__ ssrc,
                                               const float* __restrict__ C,
                                               float* __restrict__ Cp) {
  int e = blockIdx.x * 256 + threadIdx.x;
  if (e >= NE) return;
  int dst = ei[NE + e];
  int ofs = atomicAdd(&cursor[dst], 1);
  int s = start[dst] + ofs;
  es[s] = e;
  ssrc[s] = ei[e];
  Cp[s] = C[e];
}

// ---- transpose conv_mlp_w1 (NB,32,EHD) -> (NB,EHD,32)  [fallback paths only] ----
__global__ __launch_bounds__(256) void k_prep(const float* __restrict__ w1,
                                              float* __restrict__ w1t) {
  int i = blockIdx.x * 256 + threadIdx.x;
  if (i >= NBLK * 32 * EHD) return;
  int b = i / (32 * EHD);
  int j = (i / EHD) % 32;
  int k = i % EHD;
  w1t[b * EHD * 32 + k * 32 + j] = w1[i];
}

// ---- graph boundaries via binary search over sorted batch ----
__global__ void k_bounds(const int* __restrict__ batch, int* __restrict__ bounds) {
  int g = threadIdx.x;
  if (g > NG) return;
  int lo = 0, hi = NN;
  while (lo < hi) { int mid = (lo + hi) >> 1; if (batch[mid] < g) lo = mid + 1; else hi = mid; }
  bounds[g] = lo;
}

// ---- lin0 quarter-split: thread=(node, blockIdx.y=quarter) ----
__global__ __launch_bounds__(256) void k_lin0q(const float* __restrict__ x,
                                               const float* __restrict__ w,
                                               const float* __restrict__ bias,
                                               float* __restrict__ S) {
  int n = blockIdx.x * 256 + threadIdx.x;
  int q = blockIdx.y;                       // wave-uniform (blockIdx)
  if (n >= NN) return;
  float xr[FIN];
  #pragma unroll
  for (int k = 0; k < FIN; k++) xr[k] = x[n * FIN + k];
  #pragma unroll
  for (int i = 0; i < 16; i++) {
    int d = q * 16 + i;
    float a0 = bias[d], a1 = 0.f;
    #pragma unroll
    for (int k = 0; k < FIN - 1; k += 2) {
      a0 += xr[k] * w[d * FIN + k];
      a1 += xr[k + 1] * w[d * FIN + k + 1];
    }
    a0 += xr[FIN - 1] * w[d * FIN + FIN - 1];
    float acc = a0 + a1;
    S[(size_t)n * D + d] = acc > 0.f ? acc : 0.01f * acc;
  }
}

// ---- generic tiled stage: out[n, q*16+i] = act(in[n,:] @ W[q*16+i,:] + b) ----
// block = 64 nodes x 4 quarter-waves; LDS input tile; weights via s_load.
template<int ACT>   // 0 none, 1 ssp
__global__ __launch_bounds__(256) void k_stage(const float* __restrict__ in,
                                               const float* __restrict__ w,
                                               const float* __restrict__ bias,
                                               float* __restrict__ out) {
  __shared__ float tile[64 * 65];
  int tid = threadIdx.x;
  long nb = (long)blockIdx.x * 64;
  const float4* src = (const float4*)(in + nb * D);
  #pragma unroll
  for (int r = 0; r < 4; r++) {
    int idx = r * 256 + tid;
    int row = idx >> 4, c4 = idx & 15;
    float4 v = src[idx];            // coalesced; OOB rows read ws scratch (unused)
    float* dp = &tile[row * 65 + c4 * 4];
    dp[0] = v.x; dp[1] = v.y; dp[2] = v.z; dp[3] = v.w;
  }
  __syncthreads();
  int q = __builtin_amdgcn_readfirstlane(tid >> 6);  // prove wave-uniform -> s_loads
  int lane = tid & 63;
  float acc[16];
  const float* wr = w + q * 16 * D;
  #pragma unroll
  for (int i = 0; i < 16; i++) acc[i] = bias ? bias[q * 16 + i] : 0.0f;
  for (int k = 0; k < D; k++) {
    float a = tile[lane * 65 + k];       // (lane+k)%32 banks: conflict-free
    #pragma unroll
    for (int i = 0; i < 16; i++) acc[i] += a * wr[i * D + k];
  }
  __syncthreads();
  #pragma unroll
  for (int i = 0; i < 16; i++) {
    float v = acc[i];
    if (ACT == 1) v = sspf(v);
    tile[lane * 65 + q * 16 + i] = v;
  }
  __syncthreads();
  float4* dst = (float4*)(out + nb * D);
  #pragma unroll
  for (int r = 0; r < 4; r++) {
    int idx = r * 256 + tid;
    int row = idx >> 4, c4 = idx & 15;
    if (nb + row < NN) {
      const float* sp = &tile[row * 65 + c4 * 4];
      dst[idx] = make_float4(sp[0], sp[1], sp[2], sp[3]);
    }
  }
}

// ---- GRU tiled: h' = GRU(m, h); block = 64 nodes x 4 quarter-waves ----
__global__ __launch_bounds__(256) void k_gru(const float* __restrict__ m,
                                             const float* __restrict__ hin,
                                             const float* __restrict__ wih,
                                             const float* __restrict__ whh,
                                             const float* __restrict__ bih,
                                             const float* __restrict__ bhh,
                                             float* __restrict__ hout) {
  __shared__ float tm[64 * 65];
  __shared__ float th[64 * 65];
  int tid = threadIdx.x;
  long nb = (long)blockIdx.x * 64;
  const float4* ms = (const float4*)(m + nb * D);
  const float4* hs = (const float4*)(hin + nb * D);
  #pragma unroll
  for (int r = 0; r < 4; r++) {
    int idx = r * 256 + tid;
    int row = idx >> 4, c4 = idx & 15;
    float4 v = ms[idx];
    float* dp = &tm[row * 65 + c4 * 4];
    dp[0] = v.x; dp[1] = v.y; dp[2] = v.z; dp[3] = v.w;
    float4 u = hs[idx];
    float* ep = &th[row * 65 + c4 * 4];
    ep[0] = u.x; ep[1] = u.y; ep[2] = u.z; ep[3] = u.w;
  }
  __syncthreads();
  int q = __builtin_amdgcn_readfirstlane(tid >> 6);
  int lane = tid & 63;
  float ir[16], iz[16], inn[16], hr[16], hz[16], hn[16];
  #pragma unroll
  for (int i = 0; i < 16; i++) {
    int dd = q * 16 + i;
    ir[i] = bih[dd]; iz[i] = bih[D + dd]; inn[i] = bih[2 * D + dd];
    hr[i] = bhh[dd]; hz[i] = bhh[D + dd]; hn[i] = bhh[2 * D + dd];
  }
  const float* wi0 = wih + q * 16 * D;
  const float* wi1 = wih + (D + q * 16) * D;
  const float* wi2 = wih + (2 * D + q * 16) * D;
  const float* wh0 = whh + q * 16 * D;
  const float* wh1 = whh + (D + q * 16) * D;
  const float* wh2 = whh + (2 * D + q * 16) * D;
  for (int k = 0; k < D; k++) {
    float mm = tm[lane * 65 + k];
    float hh = th[lane * 65 + k];
    #pragma unroll
    for (int i = 0; i < 16; i++) {
      ir[i]  += mm * wi0[i * D + k];
      iz[i]  += mm * wi1[i * D + k];
      inn[i] += mm * wi2[i * D + k];
      hr[i]  += hh * wh0[i * D + k];
      hz[i]  += hh * wh1[i * D + k];
      hn[i]  += hh * wh2[i * D + k];
    }
  }
  __syncthreads();
  #pragma unroll
  for (int i = 0; i < 16; i++) {
    float hold = th[lane * 65 + q * 16 + i];
    float r = sigm(ir[i] + hr[i]);
    float zg = sigm(iz[i] + hz[i]);
    float nn2 = tanhf(inn[i] + r * hn[i]);
    tm[lane * 65 + q * 16 + i] = (1.0f - zg) * nn2 + zg * hold;
  }
  __syncthreads();
  float4* dst = (float4*)(hout + nb * D);
  #pragma unroll
  for (int r = 0; r < 4; r++) {
    int idx = r * 256 + tid;
    int row = idx >> 4, c4 = idx & 15;
    if (nb + row < NN) {
      const float* sp = &tm[row * 65 + c4 * 4];
      dst[idx] = make_float4(sp[0], sp[1], sp[2], sp[3]);
    }
  }
}

// ---- dense edge MLP1: T1[e,32] = relu(ea[e,:] @ W1^T + b1), coalesced ea ----
__global__ __launch_bounds__(256) void k_mlp1(const float* __restrict__ ea,
                                              const float* __restrict__ w1,
                                              const float* __restrict__ b1,
                                              float* __restrict__ T1) {
  __shared__ float tile[64 * 51];
  int tid = threadIdx.x;
  long eb = (long)blockIdx.x * 64;       // 1M % 64 == 0: no tail
  const float* src = ea + eb * EHD;
  #pragma unroll
  for (int it = 0; it < 13; it++) {
    int idx = it * 256 + tid;
    if (idx < 64 * EHD) {
      int row = idx / EHD, col = idx - row * EHD;
      tile[row * 51 + col] = src[idx];   // coalesced
    }
  }
  __syncthreads();
  int q = __builtin_amdgcn_readfirstlane(tid >> 6);
  int lane = tid & 63;
  float acc[8];
  const float* wr = w1 + q * 8 * EHD;
  #pragma unroll
  for (int i = 0; i < 8; i++) acc[i] = b1[q * 8 + i];
  for (int k = 0; k < EHD; k++) {
    float a = tile[lane * 51 + k];       // (19*lane+k)%32: conflict-free
    #pragma unroll
    for (int i = 0; i < 8; i++) acc[i] += a * wr[i * EHD + k];
  }
  __syncthreads();
  #pragma unroll
  for (int i = 0; i < 8; i++)
    tile[lane * 33 + q * 8 + i] = fmaxf(acc[i], 0.0f);
  __syncthreads();
  float4* dst = (float4*)(T1 + eb * 32);
  #pragma unroll
  for (int r = 0; r < 2; r++) {
    int idx = r * 256 + tid;
    int row = idx >> 3, c4 = idx & 7;
    const float* sp = &tile[row * 33 + c4 * 4];
    dst[idx] = make_float4(sp[0], sp[1], sp[2], sp[3]);
  }
}

// ---- fast edge kernel: gather T1 + hx rows, MLP2, store msg (no atomics) ----
__global__ __launch_bounds__(256) void k_edgef(const float* __restrict__ T1,
                                               const float* __restrict__ w2,
                                               const float* __restrict__ b2,
                                               const float* __restrict__ Cp,
                                               const int* __restrict__ ssrc,
                                               const int* __restrict__ es,
                                               const int* __restrict__ start,
                                               const float* __restrict__ hx,
                                               float* __restrict__ msgc,
                                               int n0, int n1, int cap) {
  int c0 = start[n0], c1 = start[n1];
  int o = blockIdx.x * 256 + threadIdx.x;
  int s = c0 + o;
  if (s >= c1 || o >= cap) return;
  int e = es[s];
  int src = ssrc[s];
  float cv = Cp[s];
  const float4* tp = (const float4*)(T1 + (size_t)e * 32);
  const float4* hp = (const float4*)(hx + (size_t)src * D);
  float4 tv[8];
  #pragma unroll
  for (int i = 0; i < 8; i++) tv[i] = tp[i];
  float4 hv[16];
  #pragma unroll
  for (int i = 0; i < 16; i++) hv[i] = hp[i];
  float t[32];
  #pragma unroll
  for (int i = 0; i < 8; i++) {
    t[4*i] = tv[i].x; t[4*i+1] = tv[i].y; t[4*i+2] = tv[i].z; t[4*i+3] = tv[i].w;
  }
  float4* mr = (float4*)(msgc + (size_t)o * D);
  #pragma unroll
  for (int dq = 0; dq < 16; dq++) {
    float o0[4];
    #pragma unroll
    for (int u = 0; u < 4; u++) {
      int d = dq * 4 + u;
      float a0 = b2[d], a1 = 0, a2 = 0, a3 = 0;
      #pragma unroll
      for (int j = 0; j < 32; j += 4) {
        a0 += t[j]   * w2[d * 32 + j];
        a1 += t[j+1] * w2[d * 32 + j + 1];
        a2 += t[j+2] * w2[d * 32 + j + 2];
        a3 += t[j+3] * w2[d * 32 + j + 3];
      }
      o0[u] = ((a0 + a1) + (a2 + a3)) * cv;
    }
    float4 h4 = hv[dq];
    mr[dq] = make_float4(o0[0]*h4.x, o0[1]*h4.y, o0[2]*h4.z, o0[3]*h4.w);
  }
}

// ---- mode1 fallback: CSR edge kernel with strided ea reads (round-2) ----
__global__ __launch_bounds__(256) void k_edgeg(const float* __restrict__ ea,
                                               const float* __restrict__ w1t,
                                               const float* __restrict__ b1,
                                               const float* __restrict__ w2,
                                               const float* __restrict__ b2,
                                               const float* __restrict__ C,
                                               const int* __restrict__ ei,
                                               const int* __restrict__ es,
                                               const int* __restrict__ start,
                                               const float* __restrict__ hx,
                                               float* __restrict__ msgc,
                                               int n0, int n1, int cap) {
  int c0 = start[n0], c1 = start[n1];
  int s = c0 + blockIdx.x * 256 + threadIdx.x;
  if (s >= c1 || (s - c0) >= cap) return;
  int e = es[s];
  float t[32];
  #pragma unroll
  for (int j = 0; j < 32; j++) t[j] = b1[j];
  const float2* ea2 = (const float2*)(ea + (size_t)e * EHD);
  for (int k2 = 0; k2 < EHD / 2; k2++) {
    float2 v = ea2[k2];
    #pragma unroll
    for (int j = 0; j < 32; j++) t[j] += v.x * w1t[(2 * k2) * 32 + j];
    #pragma unroll
    for (int j = 0; j < 32; j++) t[j] += v.y * w1t[(2 * k2 + 1) * 32 + j];
  }
  #pragma unroll
  for (int j = 0; j < 32; j++) t[j] = fmaxf(t[j], 0.0f);
  float cv = C[e];
  int src = ei[e];
  const float4* hr4 = (const float4*)(hx + (size_t)src * D);
  float4* mr4 = (float4*)(msgc + (size_t)(s - c0) * D);
  for (int dq = 0; dq < 16; dq++) {
    float4 hvv = hr4[dq];
    float o[4];
    #pragma unroll
    for (int u = 0; u < 4; u++) {
      int d = dq * 4 + u;
      float a0 = b2[d], a1 = 0, a2 = 0, a3 = 0;
      #pragma unroll
      for (int j = 0; j < 32; j += 4) {
        a0 += t[j]   * w2[d * 32 + j];
        a1 += t[j+1] * w2[d * 32 + j + 1];
        a2 += t[j+2] * w2[d * 32 + j + 2];
        a3 += t[j+3] * w2[d * 32 + j + 3];
      }
      o[u] = ((a0 + a1) + (a2 + a3)) * cv;
    }
    mr4[dq] = make_float4(o[0]*hvv.x, o[1]*hvv.y, o[2]*hvv.z, o[3]*hvv.w);
  }
}

// ---- gather/mean: wave per node; dinv folded ----
__global__ __launch_bounds__(256) void k_agg2(const float* __restrict__ msgc,
                                              const int* __restrict__ start,
                                              const float* __restrict__ dinv,
                                              float* __restrict__ agg,
                                              int n0, int n1, int cap) {
  int n = n0 + blockIdx.x * 4 + (threadIdx.x >> 6);
  if (n >= n1) return;
  int lane = threadIdx.x & 63;
  int c0 = start[n0];
  int s0 = start[n] - c0, s1 = start[n + 1] - c0;
  if (s1 > cap) s1 = cap;
  float a0 = 0, a1 = 0;
  int s = s0;
  for (; s + 1 < s1; s += 2) {
    a0 += msgc[(size_t)s * D + lane];
    a1 += msgc[(size_t)(s + 1) * D + lane];
  }
  if (s < s1) a0 += msgc[(size_t)s * D + lane];
  agg[(size_t)n * D + lane] = (a0 + a1) * dinv[n];
}

// ---- mode0 fallback: atomic scatter edge kernel ----
__global__ __launch_bounds__(256) void k_edge(const float* __restrict__ ea,
                                              const float* __restrict__ w1t,
                                              const float* __restrict__ b1,
                                              const float* __restrict__ w2,
                                              const float* __restrict__ b2,
                                              const float* __restrict__ C,
                                              const int* __restrict__ ei,
                                              const float* __restrict__ hx,
                                              float* __restrict__ agg) {
  int e = blockIdx.x * 256 + threadIdx.x;
  if (e >= NE) return;
  float t[32];
  #pragma unroll
  for (int j = 0; j < 32; j++) t[j] = b1[j];
  const float* ear = ea + (size_t)e * EHD;
  for (int k = 0; k < EHD; k++) {
    float a = ear[k];
    #pragma unroll
    for (int j = 0; j < 32; j++) t[j] += a * w1t[k * 32 + j];
  }
  #pragma unroll
  for (int j = 0; j < 32; j++) t[j] = fmaxf(t[j], 0.0f);
  float cv = C[e];
  int src = ei[e], dst = ei[NE + e];
  const float* hr = hx + (size_t)src * D;
  float* ar = agg + (size_t)dst * D;
  for (int d = 0; d < D; d++) {
    float a0 = b2[d], a1 = 0, a2 = 0, a3 = 0;
    #pragma unroll
    for (int j = 0; j < 32; j += 4) {
      a0 += t[j]   * w2[d * 32 + j];
      a1 += t[j+1] * w2[d * 32 + j + 1];
      a2 += t[j+2] * w2[d * 32 + j + 2];
      a3 += t[j+3] * w2[d * 32 + j + 3];
    }
    float wm = (a0 + a1) + (a2 + a3);
    atomicAdd(&ar[d], wm * cv * hr[d]);
  }
}

// ---- mode0: agg *= dinv ----
__global__ __launch_bounds__(256) void k_scale(float* __restrict__ agg,
                                               const float* __restrict__ dinv) {
  int i = blockIdx.x * 256 + threadIdx.x;
  if (i < NN * D) agg[i] *= dinv[i >> 6];
}

// ---- Set2Set LSTM step ----
__global__ __launch_bounds__(64) void k_lstm(const float* __restrict__ wih,
                                             const float* __restrict__ whh,
                                             const float* __restrict__ bih,
                                             const float* __restrict__ bhh,
                                             float* __restrict__ qstar,
                                             float* __restrict__ hl,
                                             float* __restrict__ cl) {
  int g = blockIdx.x, d = threadIdx.x;
  const float* qs = qstar + g * 2 * D;
  const float* hr = hl + g * D;
  float ai = bih[d]         + bhh[d];
  float af = bih[D + d]     + bhh[D + d];
  float ag = bih[2 * D + d] + bhh[2 * D + d];
  float ao = bih[3 * D + d] + bhh[3 * D + d];
  #pragma unroll 8
  for (int k = 0; k < 2 * D; k++) {
    float q = qs[k];
    ai += q * wih[d * 2 * D + k];
    af += q * wih[(D + d) * 2 * D + k];
    ag += q * wih[(2 * D + d) * 2 * D + k];
    ao += q * wih[(3 * D + d) * 2 * D + k];
  }
  #pragma unroll 8
  for (int k = 0; k < D; k++) {
    float h = hr[k];
    ai += h * whh[d * D + k];
    af += h * whh[(D + d) * D + k];
    ag += h * whh[(2 * D + d) * D + k];
    ao += h * whh[(3 * D + d) * D + k];
  }
  float c = sigm(af) * cl[g * D + d] + sigm(ai) * tanhf(ag);
  float hn = sigm(ao) * tanhf(c);
  cl[g * D + d] = c;
  hl[g * D + d] = hn;
  qstar[g * 2 * D + d] = hn;
}

// ---- Set2Set attention ----
__global__ __launch_bounds__(256) void k_attn(const float* __restrict__ S,
                                              const int* __restrict__ bounds,
                                              float* __restrict__ qstar,
                                              float* __restrict__ ebuf) {
  __shared__ float qv[D];
  __shared__ float red[256];
  int g = blockIdx.x, tid = threadIdx.x;
  int s = bounds[g], en = bounds[g + 1];
  if (tid < D) qv[tid] = qstar[g * 2 * D + tid];
  __syncthreads();
  float lmax = -1e30f;
  for (int n = s + tid; n < en; n += 256) {
    const float4* Sv = (const float4*)(S + (size_t)n * D);
    float a0 = 0, a1 = 0, a2 = 0, a3 = 0;
    #pragma unroll
    for (int q = 0; q < 16; q++) {
      float4 v = Sv[q];
      a0 += v.x * qv[4*q]; a1 += v.y * qv[4*q+1];
      a2 += v.z * qv[4*q+2]; a3 += v.w * qv[4*q+3];
    }
    float e = (a0 + a1) + (a2 + a3);
    ebuf[n] = e;
    lmax = fmaxf(lmax, e);
  }
  red[tid] = lmax; __syncthreads();
  for (int st = 128; st > 0; st >>= 1) {
    if (tid < st) red[tid] = fmaxf(red[tid], red[tid + st]);
    __syncthreads();
  }
  float smax = red[0]; __syncthreads();
  float lsum = 0;
  for (int n = s + tid; n < en; n += 256) {
    float p = expf(ebuf[n] - smax);
    ebuf[n] = p;
    lsum += p;
  }
  red[tid] = lsum; __syncthreads();
  for (int st = 128; st > 0; st >>= 1) {
    if (tid < st) red[tid] += red[tid + st];
    __syncthreads();
  }
  float inv = red[0] > 0.f ? 1.0f / red[0] : 0.0f;
  __syncthreads();
  int grp = tid >> 6, d = tid & 63;
  float acc = 0;
  for (int n = s + grp; n < en; n += 4)
    acc += ebuf[n] * S[(size_t)n * D + d];
  red[tid] = acc; __syncthreads();
  if (tid < D)
    qstar[g * 2 * D + D + tid] =
        (red[tid] + red[64 + tid] + red[128 + tid] + red[192 + tid]) * inv;
}

// ---- final head ----
__global__ __launch_bounds__(64) void k_final(const float* __restrict__ qstar,
                                              const float* __restrict__ w1,
                                              const float* __restrict__ b1,
                                              const float* __restrict__ w2,
                                              const float* __restrict__ b2,
                                              const int* __restrict__ z,
                                              const float* __restrict__ eref,
                                              const float* __restrict__ aref,
                                              const int* __restrict__ bounds,
                                              float* __restrict__ outp) {
  __shared__ float red[D];
  int g = blockIdx.x, d = threadIdx.x;
  const float* qs = qstar + g * 2 * D;
  float a0 = 0, a1 = 0, a2 = 0, a3 = 0;
  #pragma unroll
  for (int k = 0; k < 2 * D; k += 4) {
    a0 += qs[k]   * w1[d * 2 * D + k];
    a1 += qs[k+1] * w1[d * 2 * D + k + 1];
    a2 += qs[k+2] * w1[d * 2 * D + k + 2];
    a3 += qs[k+3] * w1[d * 2 * D + k + 3];
  }
  float gv = fmaxf((a0 + a1) + (a2 + a3) + b1[d], 0.0f);
  red[d] = gv * w2[d];
  __syncthreads();
  for (int st = 32; st > 0; st >>= 1) {
    if (d < st) red[d] += red[d + st];
    __syncthreads();
  }
  float energy = red[0] + b2[0];
  __syncthreads();
  int s = bounds[g], en = bounds[g + 1];
  float racc = 0;
  for (int n = s + d; n < en; n += 64) {
    int zz = z[n];
    racc += eref[zz] + aref[zz];
  }
  red[d] = racc; __syncthreads();
  for (int st = 32; st > 0; st >>= 1) {
    if (d < st) red[d] += red[d + st];
    __syncthreads();
  }
  if (d == 0) outp[g] = energy + red[0];
}

extern "C" void kernel_launch(void* const* d_in, const int* in_sizes, int n_in,
                              void* d_out, int out_size, void* d_ws, size_t ws_size,
                              hipStream_t stream) {
  const float* x      = (const float*)d_in[0];
  const int*   ei     = (const int*)d_in[1];
  const float* ew     = (const float*)d_in[2];
  const float* ea     = (const float*)d_in[3];
  const int*   z      = (const int*)d_in[4];
  const int*   batch  = (const int*)d_in[5];
  const float* lin0_w = (const float*)d_in[6];
  const float* lin0_b = (const float*)d_in[7];
  const float* cw1    = (const float*)d_in[8];
  const float* cb1    = (const float*)d_in[9];
  const float* cw2    = (const float*)d_in[10];
  const float* cb2    = (const float*)d_in[11];
  const float* cl1w   = (const float*)d_in[12];
  const float* cl2w   = (const float*)d_in[13];
  const float* cl2b   = (const float*)d_in[14];
  const float* cl3w   = (const float*)d_in[15];
  const float* cl3b   = (const float*)d_in[16];
  const float* gwih   = (const float*)d_in[17];
  const float* gwhh   = (const float*)d_in[18];
  const float* gbih   = (const float*)d_in[19];
  const float* gbhh   = (const float*)d_in[20];
  const float* lwih   = (const float*)d_in[21];
  const float* lwhh   = (const float*)d_in[22];
  const float* lbih   = (const float*)d_in[23];
  const float* lbhh   = (const float*)d_in[24];
  const float* l1w    = (const float*)d_in[25];
  const float* l1b    = (const float*)d_in[26];
  const float* l2w    = (const float*)d_in[27];
  const float* l2b    = (const float*)d_in[28];
  const float* aref   = (const float*)d_in[29];
  const float* eref   = (const float*)d_in[30];
  float* outp = (float*)d_out;

  const long NND = (long)NN * D;   // 3.2M
  float* f = (float*)d_ws;
  long cur = 0;
  long oS0 = cur;   cur += NND;
  long oS1 = cur;   cur += NND;
  long oHX = cur;   cur += NND;    // aliased with lin2 output (v1)
  long oAG = cur;   cur += NND;    // aliased with lin3 output (m)
  long oC  = cur;   cur += NE;
  long oCP = cur;   cur += NE;
  long oDI = cur;   cur += 50176;
  long oEB = cur;   cur += 50176;  // ebuf, aliased with degi/cursor
  long oQ  = cur;   cur += NG * 2 * D;
  long oHL = cur;   cur += NG * D;
  long oCL = cur;   cur += NG * D;
  long oW1 = cur;   cur += 8192;
  long oBN = cur;   cur += 256;
  long oES = cur;   cur += NE;
  long oSR = cur;   cur += NE;
  long oST = cur;   cur += 51200;
  long baseEnd = cur;

  float* S0   = f + oS0;
  float* S1   = f + oS1;
  float* hxb  = f + oHX;
  float* aggb = f + oAG;
  float* Cb   = f + oC;
  float* Cp   = f + oCP;
  float* dinv = f + oDI;
  float* ebuf = f + oEB;
  int*   degi = (int*)(f + oEB);
  float* qstar= f + oQ;
  float* hl   = f + oHL;
  float* cls  = f + oCL;
  float* w1t  = f + oW1;
  int*   bounds = (int*)(f + oBN);
  int*   es   = (int*)(f + oES);
  int*   ssrc = (int*)(f + oSR);
  int*   startA = (int*)(f + oST);

  long wsF = (long)(ws_size / 4);
  long rem = wsF - baseEnd;
  long t1f = (long)NE * 32;
  int mode = 0, NCH = 0;
  long capChunk = 0, oT1 = 0, oMSG = 0;
  for (int c = 8; c <= 64; c++) {
    long nper = (NN + c - 1) / c;
    long need = ((long)NE * nper / NN) * 13 / 10 + 4096;
    if (t1f + need * D <= rem) { mode = 2; NCH = c; capChunk = need; break; }
  }
  if (!mode) {
    for (int c = 8; c <= 64; c++) {
      long nper = (NN + c - 1) / c;
      long need = ((long)NE * nper / NN) * 13 / 10 + 4096;
      if (need * D <= rem) { mode = 1; NCH = c; capChunk = need; break; }
    }
  }
  if (mode == 2) { oT1 = baseEnd; oMSG = oT1 + t1f; }
  else           { oMSG = baseEnd; }
  float* T1   = f + oT1;
  float* msgc = f + oMSG;

  hipMemsetAsync(degi, 0, NN * sizeof(int), stream);
  hipMemsetAsync(qstar, 0, (NG * 2 * D + 2 * NG * D) * sizeof(float), stream);

  if (mode < 2) k_prep<<<19, 256, 0, stream>>>(cw1, w1t);
  k_env<<<(NE + 255) / 256, 256, 0, stream>>>(ew, ei, Cb, degi);
  if (mode) {
    k_scan<<<1, 1024, 0, stream>>>(degi, startA, dinv);
    k_slot2<<<(NE + 255) / 256, 256, 0, stream>>>(ei, startA, degi, es, ssrc, Cb, Cp);
  } else {
    k_dinv<<<(NN + 255) / 256, 256, 0, stream>>>(degi, dinv);
  }
  k_lin0q<<<dim3((NN + 255) / 256, 4), 256, 0, stream>>>(x, lin0_w, lin0_b, S0);
  k_bounds<<<1, 192, 0, stream>>>(batch, bounds);

  const int NBK = (NN + 63) / 64;   // node-tile blocks
  for (int b = 0; b < NBLK; b++) {
    float* Sin  = (b & 1) ? S1 : S0;
    float* Sout = (b & 1) ? S0 : S1;
    // hx = Sin @ lin1^T
    k_stage<0><<<NBK, 256, 0, stream>>>(Sin, cl1w + b * D * D, nullptr, hxb);
    if (mode == 2) {
      k_mlp1<<<NE / 64, 256, 0, stream>>>(ea, cw1 + b * 32 * EHD, cb1 + b * 32, T1);
      int nodesPer = (NN + NCH - 1) / NCH;
      for (int c = 0; c < NCH; c++) {
        int n0 = c * nodesPer;
        int n1 = n0 + nodesPer; if (n1 > NN) n1 = NN;
        if (n0 >= n1) break;
        k_edgef<<<(int)((capChunk + 255) / 256), 256, 0, stream>>>(
            T1, cw2 + b * D * 32, cb2 + b * D, Cp, ssrc, es, startA, hxb,
            msgc, n0, n1, (int)capChunk);
        k_agg2<<<(n1 - n0 + 3) / 4, 256, 0, stream>>>(msgc, startA, dinv, aggb,
                                                      n0, n1, (int)capChunk);
      }
    } else if (mode == 1) {
      int nodesPer = (NN + NCH - 1) / NCH;
      for (int c = 0; c < NCH; c++) {
        int n0 = c * nodesPer;
        int n1 = n0 + nodesPer; if (n1 > NN) n1 = NN;
        if (n0 >= n1) break;
        k_edgeg<<<(int)((capChunk + 255) / 256), 256, 0, stream>>>(
            ea, w1t + b * EHD * 32, cb1 + b * 32, cw2 + b * D * 32, cb2 + b * D,
            Cb, ei, es, startA, hxb, msgc, n0, n1, (int)capChunk);
        k_agg2<<<(n1 - n0 + 3) / 4, 256, 0, stream>>>(msgc, startA, dinv, aggb,
                                                      n0, n1, (int)capChunk);
      }
    } else {
      hipMemsetAsync(aggb, 0, NND * sizeof(float), stream);
      k_edge<<<(NE + 255) / 256, 256, 0, stream>>>(
          ea, w1t + b * EHD * 32, cb1 + b * 32, cw2 + b * D * 32, cb2 + b * D,
          Cb, ei, hxb, aggb);
      k_scale<<<(NN * D + 255) / 256, 256, 0, stream>>>(aggb, dinv);
    }
    // v1 = ssp(agg @ lin2^T + b2)   (agg already mean'd)
    k_stage<1><<<NBK, 256, 0, stream>>>(aggb, cl2w + b * D * D, cl2b + b * D, hxb);
    // m = v1 @ lin3^T + b3
    k_stage<0><<<NBK, 256, 0, stream>>>(hxb, cl3w + b * D * D, cl3b + b * D, aggb);
    // h' = GRU(m, h)
    k_gru<<<NBK, 256, 0, stream>>>(aggb, Sin, gwih, gwhh, gbih, gbhh, Sout);
  }

  float* Sfin = (NBLK & 1) ? S1 : S0;
  for (int it = 0; it < 3; it++) {
    k_lstm<<<NG, 64, 0, stream>>>(lwih, lwhh, lbih, lbhh, qstar, hl, cls);
    k_attn<<<NG, 256, 0, stream>>>(Sfin, bounds, qstar, ebuf);
  }

  k_final<<<NG, 64, 0, stream>>>(qstar, l1w, l1b, l2w, l2b, z, eref, aref,
                                 bounds, outp);
}

// Round 4
// 1765.002 us; speedup vs baseline: 6.5824x; 1.1621x over previous
//
#include <hip/hip_runtime.h>
#include <math.h>

#define NN 50000      // nodes
#define NE 1000000    // edges
#define D 64          // hidden
#define FIN 19
#define EHD 50        // edge attr dim
#define NG 128        // graphs
#define NBLK 3
#define NB1 196       // (NN+255)/256

#define PI_OVER_CUT 0.6283185307179586f
#define LN2F 0.6931471805599453f

static __device__ __forceinline__ float sspf(float x) {
  return fmaxf(x, 0.0f) + log1pf(expf(-fabsf(x))) - LN2F;
}
static __device__ __forceinline__ float sigm(float x) {
  return 1.0f / (1.0f + expf(-x));
}

// ---- degree count ----
__global__ __launch_bounds__(256) void k_deg(const int* __restrict__ ei,
                                             int* __restrict__ degi) {
  int e = blockIdx.x * 256 + threadIdx.x;
  if (e < NE) atomicAdd(&degi[ei[NE + e]], 1);
}

// ---- parallel scan, pass 1: per-256-block exclusive scan + block sums ----
__global__ __launch_bounds__(256) void k_scan1(int* __restrict__ degi,
                                               int* __restrict__ start,
                                               float* __restrict__ dinv,
                                               int* __restrict__ bsum) {
  __shared__ int sc[256];
  int t = threadIdx.x;
  int i = blockIdx.x * 256 + t;
  int d = (i < NN) ? degi[i] : 0;
  sc[t] = d; __syncthreads();
  for (int off = 1; off < 256; off <<= 1) {
    int u = (t >= off) ? sc[t - off] : 0;
    __syncthreads();
    sc[t] += u;
    __syncthreads();
  }
  if (i < NN) {
    start[i] = sc[t] - d;                 // block-local exclusive
    dinv[i] = 1.0f / fmaxf((float)d, 1.0f);
    degi[i] = 0;                          // becomes cursor for k_slot2
  }
  if (t == 255) bsum[blockIdx.x] = sc[255];
}

// ---- scan pass 2: exclusive scan of the 196 block sums ----
__global__ __launch_bounds__(256) void k_scan2(int* __restrict__ bsum) {
  __shared__ int sc[256];
  int t = threadIdx.x;
  int v = (t < NB1) ? bsum[t] : 0;
  sc[t] = v; __syncthreads();
  for (int off = 1; off < 256; off <<= 1) {
    int u = (t >= off) ? sc[t - off] : 0;
    __syncthreads();
    sc[t] += u;
    __syncthreads();
  }
  bsum[t] = sc[t] - v;
}

// ---- scan pass 3: add block offsets; start[NN] = NE ----
__global__ __launch_bounds__(256) void k_scan3(int* __restrict__ start,
                                               const int* __restrict__ bsum) {
  int i = blockIdx.x * 256 + threadIdx.x;
  if (i < NN) start[i] += bsum[blockIdx.x];
  if (i == 0) start[NN] = NE;
}

// ---- fallback dinv (atomic path) ----
__global__ __launch_bounds__(256) void k_dinv(const int* __restrict__ degi,
                                              float* __restrict__ dinv) {
  int n = blockIdx.x * 256 + threadIdx.x;
  if (n < NN) dinv[n] = 1.0f / fmaxf((float)degi[n], 1.0f);
}

// ---- envelope in edge order (mode0 fallback only) ----
__global__ __launch_bounds__(256) void k_envC(const float* __restrict__ ew,
                                              float* __restrict__ C) {
  int e = blockIdx.x * 256 + threadIdx.x;
  if (e < NE) C[e] = cosf(ew[e] * PI_OVER_CUT) * 0.5f + 0.5f;
}

// ---- CSR slot assignment: inv[e]=s, permuted src & envelope ----
__global__ __launch_bounds__(256) void k_slot2(const int* __restrict__ ei,
                                               const float* __restrict__ ew,
                                               const int* __restrict__ start,
                                               int* __restrict__ cursor,
                                               int* __restrict__ es,
                                               int* __restrict__ inv,
                                               int* __restrict__ ssrc,
                                               float* __restrict__ Cp) {
  int e = blockIdx.x * 256 + threadIdx.x;
  if (e >= NE) return;
  int dst = ei[NE + e];
  int ofs = atomicAdd(&cursor[dst], 1);
  int s = start[dst] + ofs;
  es[s] = e;
  inv[e] = s;
  ssrc[s] = ei[e];
  Cp[s] = cosf(ew[e] * PI_OVER_CUT) * 0.5f + 0.5f;
}

// ---- transpose conv_mlp_w1 (fallback paths only) ----
__global__ __launch_bounds__(256) void k_prep(const float* __restrict__ w1,
                                              float* __restrict__ w1t) {
  int i = blockIdx.x * 256 + threadIdx.x;
  if (i >= NBLK * 32 * EHD) return;
  int b = i / (32 * EHD);
  int j = (i / EHD) % EHD ? 0 : 0;  // placeholder avoid warn
  j = (i / EHD) % 32;
  int k = i % EHD;
  w1t[b * EHD * 32 + k * 32 + j] = w1[i];
}

// ---- graph boundaries ----
__global__ void k_bounds(const int* __restrict__ batch, int* __restrict__ bounds) {
  int g = threadIdx.x;
  if (g > NG) return;
  int lo = 0, hi = NN;
  while (lo < hi) { int mid = (lo + hi) >> 1; if (batch[mid] < g) lo = mid + 1; else hi = mid; }
  bounds[g] = lo;
}

// ---- lin0 quarter-split ----
__global__ __launch_bounds__(256) void k_lin0q(const float* __restrict__ x,
                                               const float* __restrict__ w,
                                               const float* __restrict__ bias,
                                               float* __restrict__ S) {
  int n = blockIdx.x * 256 + threadIdx.x;
  int q = blockIdx.y;
  if (n >= NN) return;
  float xr[FIN];
  #pragma unroll
  for (int k = 0; k < FIN; k++) xr[k] = x[n * FIN + k];
  #pragma unroll
  for (int i = 0; i < 16; i++) {
    int d = q * 16 + i;
    float a0 = bias[d], a1 = 0.f;
    #pragma unroll
    for (int k = 0; k < FIN - 1; k += 2) {
      a0 += xr[k] * w[d * FIN + k];
      a1 += xr[k + 1] * w[d * FIN + k + 1];
    }
    a0 += xr[FIN - 1] * w[d * FIN + FIN - 1];
    float acc = a0 + a1;
    S[(size_t)n * D + d] = acc > 0.f ? acc : 0.01f * acc;
  }
}

// ---- tiled GEMV stage (initial hx only): out = in @ W^T ----
template<int ACT>
__global__ __launch_bounds__(256) void k_stage(const float* __restrict__ in,
                                               const float* __restrict__ w,
                                               const float* __restrict__ bias,
                                               float* __restrict__ out) {
  __shared__ float tile[64 * 65];
  int tid = threadIdx.x;
  long nb = (long)blockIdx.x * 64;
  const float4* src = (const float4*)(in + nb * D);
  #pragma unroll
  for (int r = 0; r < 4; r++) {
    int idx = r * 256 + tid;
    int row = idx >> 4, c4 = idx & 15;
    float4 v = src[idx];
    float* dp = &tile[row * 65 + c4 * 4];
    dp[0] = v.x; dp[1] = v.y; dp[2] = v.z; dp[3] = v.w;
  }
  __syncthreads();
  int q = __builtin_amdgcn_readfirstlane(tid >> 6);
  int lane = tid & 63;
  float acc[16];
  const float* wr = w + q * 16 * D;
  #pragma unroll
  for (int i = 0; i < 16; i++) acc[i] = bias ? bias[q * 16 + i] : 0.0f;
  for (int k = 0; k < D; k++) {
    float a = tile[lane * 65 + k];
    #pragma unroll
    for (int i = 0; i < 16; i++) acc[i] += a * wr[i * D + k];
  }
  __syncthreads();
  #pragma unroll
  for (int i = 0; i < 16; i++) {
    float v = acc[i];
    if (ACT == 1) v = sspf(v);
    tile[lane * 65 + q * 16 + i] = v;
  }
  __syncthreads();
  float4* dst = (float4*)(out + nb * D);
  #pragma unroll
  for (int r = 0; r < 4; r++) {
    int idx = r * 256 + tid;
    int row = idx >> 4, c4 = idx & 15;
    if (nb + row < NN) {
      const float* sp = &tile[row * 65 + c4 * 4];
      dst[idx] = make_float4(sp[0], sp[1], sp[2], sp[3]);
    }
  }
}

// ---- dense edge MLP1, writes T1 in CSR order via inv[e] ----
__global__ __launch_bounds__(256) void k_mlp1(const float* __restrict__ ea,
                                              const float* __restrict__ w1,
                                              const float* __restrict__ b1,
                                              const int* __restrict__ inv,
                                              float* __restrict__ T1) {
  __shared__ float tile[64 * 51];
  int tid = threadIdx.x;
  long eb = (long)blockIdx.x * 64;       // 1M % 64 == 0
  const float* src = ea + eb * EHD;
  #pragma unroll
  for (int it = 0; it < 13; it++) {
    int idx = it * 256 + tid;
    if (idx < 64 * EHD) {
      int row = idx / EHD, col = idx - row * EHD;
      tile[row * 51 + col] = src[idx];
    }
  }
  __syncthreads();
  int q = __builtin_amdgcn_readfirstlane(tid >> 6);
  int lane = tid & 63;
  float acc[8];
  const float* wr = w1 + q * 8 * EHD;
  #pragma unroll
  for (int i = 0; i < 8; i++) acc[i] = b1[q * 8 + i];
  for (int k = 0; k < EHD; k++) {
    float a = tile[lane * 51 + k];
    #pragma unroll
    for (int i = 0; i < 8; i++) acc[i] += a * wr[i * EHD + k];
  }
  __syncthreads();
  #pragma unroll
  for (int i = 0; i < 8; i++)
    tile[lane * 33 + q * 8 + i] = fmaxf(acc[i], 0.0f);
  __syncthreads();
  #pragma unroll
  for (int r = 0; r < 2; r++) {
    int idx = r * 256 + tid;
    int row = idx >> 3, c4 = idx & 7;
    int srow = inv[eb + row];
    float4* dst = (float4*)(T1 + (size_t)srow * 32);
    const float* sp = &tile[row * 33 + c4 * 4];
    dst[c4] = make_float4(sp[0], sp[1], sp[2], sp[3]);
  }
}

// ---- fused MLP2 + aggregate: wave per node, lane d owns output dim d ----
// w2 row d in 32 VGPRs; edge T1 rows (CSR-contiguous) broadcast via
// wave-private LDS (explicit lgkmcnt wait, NO barrier in divergent loop).
__global__ __launch_bounds__(256) void k_fagg(const float* __restrict__ T1,
                                              const float* __restrict__ w2,
                                              const float* __restrict__ b2,
                                              const float* __restrict__ Cp,
                                              const int* __restrict__ ssrc,
                                              const int* __restrict__ start,
                                              const float* __restrict__ hx,
                                              const float* __restrict__ dinv,
                                              float* __restrict__ agg) {
  __shared__ float tb[4 * 64];
  int tid = threadIdx.x;
  int w = tid >> 6, lane = tid & 63;
  int n = blockIdx.x * 4 + w;
  if (n >= NN) return;
  float w2r[32];
  const float4* w2v = (const float4*)(w2 + lane * 32);
  #pragma unroll
  for (int q = 0; q < 8; q++) {
    float4 v = w2v[q];
    w2r[4*q] = v.x; w2r[4*q+1] = v.y; w2r[4*q+2] = v.z; w2r[4*q+3] = v.w;
  }
  float b2d = b2[lane];
  int s0 = start[n], s1 = start[n + 1];
  float acc = 0.0f;
  float* tw = tb + w * 64;
  const float4* t4 = (const float4*)tw;
  int s = s0;
  for (; s + 1 < s1; s += 2) {
    int sl = s + (lane >> 5);
    tw[lane] = T1[(size_t)sl * 32 + (lane & 31)];   // halfwave0->e0, halfwave1->e1
    asm volatile("s_waitcnt lgkmcnt(0)" ::: "memory");
    float cv0 = Cp[s], cv1 = Cp[s + 1];
    int r0 = ssrc[s], r1 = ssrc[s + 1];
    float h0 = hx[(size_t)r0 * D + lane];
    float h1 = hx[(size_t)r1 * D + lane];
    float d0 = b2d, e0 = 0.f, d1 = b2d, e1 = 0.f;
    #pragma unroll
    for (int qq = 0; qq < 8; qq++) {
      float4 ta = t4[qq];
      d0 += w2r[4*qq]   * ta.x;
      e0 += w2r[4*qq+1] * ta.y;
      d0 += w2r[4*qq+2] * ta.z;
      e0 += w2r[4*qq+3] * ta.w;
      float4 tc = t4[8 + qq];
      d1 += w2r[4*qq]   * tc.x;
      e1 += w2r[4*qq+1] * tc.y;
      d1 += w2r[4*qq+2] * tc.z;
      e1 += w2r[4*qq+3] * tc.w;
    }
    acc += (d0 + e0) * cv0 * h0 + (d1 + e1) * cv1 * h1;
  }
  if (s < s1) {
    if (lane < 32) tw[lane] = T1[(size_t)s * 32 + lane];
    asm volatile("s_waitcnt lgkmcnt(0)" ::: "memory");
    float cv0 = Cp[s];
    int r0 = ssrc[s];
    float h0 = hx[(size_t)r0 * D + lane];
    float d0 = b2d, e0 = 0.f;
    #pragma unroll
    for (int qq = 0; qq < 8; qq++) {
      float4 ta = t4[qq];
      d0 += w2r[4*qq]   * ta.x;
      e0 += w2r[4*qq+1] * ta.y;
      d0 += w2r[4*qq+2] * ta.z;
      e0 += w2r[4*qq+3] * ta.w;
    }
    acc += (d0 + e0) * cv0 * h0;
  }
  agg[(size_t)n * D + lane] = acc * dinv[n];
}

// ---- fused node pipeline: lin2+ssp -> lin3 -> GRU -> (optional) next hx ----
__global__ __launch_bounds__(256) void k_nodeblk(const float* __restrict__ agg,
                                                 const float* __restrict__ hin,
                                                 const float* __restrict__ w2,
                                                 const float* __restrict__ b2,
                                                 const float* __restrict__ w3,
                                                 const float* __restrict__ b3,
                                                 const float* __restrict__ wih,
                                                 const float* __restrict__ whh,
                                                 const float* __restrict__ bih,
                                                 const float* __restrict__ bhh,
                                                 float* __restrict__ hout,
                                                 const float* __restrict__ w1n,
                                                 float* __restrict__ hxout) {
  __shared__ float tA[64 * 65];
  __shared__ float tH[64 * 65];
  int tid = threadIdx.x;
  long nb = (long)blockIdx.x * 64;
  const float4* as = (const float4*)(agg + nb * D);
  const float4* hs = (const float4*)(hin + nb * D);
  #pragma unroll
  for (int r = 0; r < 4; r++) {
    int idx = r * 256 + tid;
    int row = idx >> 4, c4 = idx & 15;
    float4 v = as[idx];
    float* dp = &tA[row * 65 + c4 * 4];
    dp[0] = v.x; dp[1] = v.y; dp[2] = v.z; dp[3] = v.w;
    float4 u = hs[idx];
    float* ep = &tH[row * 65 + c4 * 4];
    ep[0] = u.x; ep[1] = u.y; ep[2] = u.z; ep[3] = u.w;
  }
  __syncthreads();
  int q = __builtin_amdgcn_readfirstlane(tid >> 6);
  int lane = tid & 63;
  // phase 1: v1 = ssp(agg @ w2^T + b2)
  {
    float acc[16];
    const float* wr = w2 + q * 16 * D;
    #pragma unroll
    for (int i = 0; i < 16; i++) acc[i] = b2[q * 16 + i];
    for (int k = 0; k < D; k++) {
      float a = tA[lane * 65 + k];
      #pragma unroll
      for (int i = 0; i < 16; i++) acc[i] += a * wr[i * D + k];
    }
    __syncthreads();
    #pragma unroll
    for (int i = 0; i < 16; i++) tA[lane * 65 + q * 16 + i] = sspf(acc[i]);
    __syncthreads();
  }
  // phase 2: m = v1 @ w3^T + b3
  {
    float acc[16];
    const float* wr = w3 + q * 16 * D;
    #pragma unroll
    for (int i = 0; i < 16; i++) acc[i] = b3[q * 16 + i];
    for (int k = 0; k < D; k++) {
      float a = tA[lane * 65 + k];
      #pragma unroll
      for (int i = 0; i < 16; i++) acc[i] += a * wr[i * D + k];
    }
    __syncthreads();
    #pragma unroll
    for (int i = 0; i < 16; i++) tA[lane * 65 + q * 16 + i] = acc[i];
    __syncthreads();
  }
  // phase 3: GRU
  {
    float ir[16], iz[16], inn[16], hr[16], hz[16], hn[16];
    #pragma unroll
    for (int i = 0; i < 16; i++) {
      int dd = q * 16 + i;
      ir[i] = bih[dd]; iz[i] = bih[D + dd]; inn[i] = bih[2 * D + dd];
      hr[i] = bhh[dd]; hz[i] = bhh[D + dd]; hn[i] = bhh[2 * D + dd];
    }
    const float* wi0 = wih + q * 16 * D;
    const float* wi1 = wih + (D + q * 16) * D;
    const float* wi2 = wih + (2 * D + q * 16) * D;
    const float* wh0 = whh + q * 16 * D;
    const float* wh1 = whh + (D + q * 16) * D;
    const float* wh2 = whh + (2 * D + q * 16) * D;
    for (int k = 0; k < D; k++) {
      float mm = tA[lane * 65 + k];
      float hh = tH[lane * 65 + k];
      #pragma unroll
      for (int i = 0; i < 16; i++) {
        ir[i]  += mm * wi0[i * D + k];
        iz[i]  += mm * wi1[i * D + k];
        inn[i] += mm * wi2[i * D + k];
        hr[i]  += hh * wh0[i * D + k];
        hz[i]  += hh * wh1[i * D + k];
        hn[i]  += hh * wh2[i * D + k];
      }
    }
    __syncthreads();
    #pragma unroll
    for (int i = 0; i < 16; i++) {
      float hold = tH[lane * 65 + q * 16 + i];
      float r = sigm(ir[i] + hr[i]);
      float zg = sigm(iz[i] + hz[i]);
      float nn2 = tanhf(inn[i] + r * hn[i]);
      tA[lane * 65 + q * 16 + i] = (1.0f - zg) * nn2 + zg * hold;
    }
    __syncthreads();
  }
  // store h'
  float4* dst = (float4*)(hout + nb * D);
  #pragma unroll
  for (int r = 0; r < 4; r++) {
    int idx = r * 256 + tid;
    int row = idx >> 4, c4 = idx & 15;
    if (nb + row < NN) {
      const float* sp = &tA[row * 65 + c4 * 4];
      dst[idx] = make_float4(sp[0], sp[1], sp[2], sp[3]);
    }
  }
  // phase 4: hx for next block = h' @ w1n^T
  if (w1n) {
    float acc[16];
    const float* wr = w1n + q * 16 * D;
    #pragma unroll
    for (int i = 0; i < 16; i++) acc[i] = 0.0f;
    for (int k = 0; k < D; k++) {
      float a = tA[lane * 65 + k];
      #pragma unroll
      for (int i = 0; i < 16; i++) acc[i] += a * wr[i * D + k];
    }
    __syncthreads();
    #pragma unroll
    for (int i = 0; i < 16; i++) tH[lane * 65 + q * 16 + i] = acc[i];
    __syncthreads();
    float4* dh = (float4*)(hxout + nb * D);
    #pragma unroll
    for (int r = 0; r < 4; r++) {
      int idx = r * 256 + tid;
      int row = idx >> 4, c4 = idx & 15;
      if (nb + row < NN) {
        const float* sp = &tH[row * 65 + c4 * 4];
        dh[idx] = make_float4(sp[0], sp[1], sp[2], sp[3]);
      }
    }
  }
}

// ---- mode1 fallback: CSR edge kernel, strided ea ----
__global__ __launch_bounds__(256) void k_edgeg(const float* __restrict__ ea,
                                               const float* __restrict__ w1t,
                                               const float* __restrict__ b1,
                                               const float* __restrict__ w2,
                                               const float* __restrict__ b2,
                                               const float* __restrict__ Cp,
                                               const int* __restrict__ ssrc,
                                               const int* __restrict__ es,
                                               const int* __restrict__ start,
                                               const float* __restrict__ hx,
                                               float* __restrict__ msgc,
                                               int n0, int n1, int cap) {
  int c0 = start[n0], c1 = start[n1];
  int s = c0 + blockIdx.x * 256 + threadIdx.x;
  if (s >= c1 || (s - c0) >= cap) return;
  int e = es[s];
  float t[32];
  #pragma unroll
  for (int j = 0; j < 32; j++) t[j] = b1[j];
  const float2* ea2 = (const float2*)(ea + (size_t)e * EHD);
  for (int k2 = 0; k2 < EHD / 2; k2++) {
    float2 v = ea2[k2];
    #pragma unroll
    for (int j = 0; j < 32; j++) t[j] += v.x * w1t[(2 * k2) * 32 + j];
    #pragma unroll
    for (int j = 0; j < 32; j++) t[j] += v.y * w1t[(2 * k2 + 1) * 32 + j];
  }
  #pragma unroll
  for (int j = 0; j < 32; j++) t[j] = fmaxf(t[j], 0.0f);
  float cv = Cp[s];
  int src = ssrc[s];
  const float4* hr4 = (const float4*)(hx + (size_t)src * D);
  float4* mr4 = (float4*)(msgc + (size_t)(s - c0) * D);
  for (int dq = 0; dq < 16; dq++) {
    float4 hvv = hr4[dq];
    float o[4];
    #pragma unroll
    for (int u = 0; u < 4; u++) {
      int d = dq * 4 + u;
      float a0 = b2[d], a1 = 0, a2 = 0, a3 = 0;
      #pragma unroll
      for (int j = 0; j < 32; j += 4) {
        a0 += t[j]   * w2[d * 32 + j];
        a1 += t[j+1] * w2[d * 32 + j + 1];
        a2 += t[j+2] * w2[d * 32 + j + 2];
        a3 += t[j+3] * w2[d * 32 + j + 3];
      }
      o[u] = ((a0 + a1) + (a2 + a3)) * cv;
    }
    mr4[dq] = make_float4(o[0]*hvv.x, o[1]*hvv.y, o[2]*hvv.z, o[3]*hvv.w);
  }
}

// ---- mode1: gather/mean ----
__global__ __launch_bounds__(256) void k_agg2(const float* __restrict__ msgc,
                                              const int* __restrict__ start,
                                              const float* __restrict__ dinv,
                                              float* __restrict__ agg,
                                              int n0, int n1, int cap) {
  int n = n0 + blockIdx.x * 4 + (threadIdx.x >> 6);
  if (n >= n1) return;
  int lane = threadIdx.x & 63;
  int c0 = start[n0];
  int s0 = start[n] - c0, s1 = start[n + 1] - c0;
  if (s1 > cap) s1 = cap;
  float a0 = 0, a1 = 0;
  int s = s0;
  for (; s + 1 < s1; s += 2) {
    a0 += msgc[(size_t)s * D + lane];
    a1 += msgc[(size_t)(s + 1) * D + lane];
  }
  if (s < s1) a0 += msgc[(size_t)s * D + lane];
  agg[(size_t)n * D + lane] = (a0 + a1) * dinv[n];
}

// ---- mode0 fallback: atomic scatter ----
__global__ __launch_bounds__(256) void k_edge(const float* __restrict__ ea,
                                              const float* __restrict__ w1t,
                                              const float* __restrict__ b1,
                                              const float* __restrict__ w2,
                                              const float* __restrict__ b2,
                                              const float* __restrict__ C,
                                              const int* __restrict__ ei,
                                              const float* __restrict__ hx,
                                              float* __restrict__ agg) {
  int e = blockIdx.x * 256 + threadIdx.x;
  if (e >= NE) return;
  float t[32];
  #pragma unroll
  for (int j = 0; j < 32; j++) t[j] = b1[j];
  const float* ear = ea + (size_t)e * EHD;
  for (int k = 0; k < EHD; k++) {
    float a = ear[k];
    #pragma unroll
    for (int j = 0; j < 32; j++) t[j] += a * w1t[k * 32 + j];
  }
  #pragma unroll
  for (int j = 0; j < 32; j++) t[j] = fmaxf(t[j], 0.0f);
  float cv = C[e];
  int src = ei[e], dst = ei[NE + e];
  const float* hr = hx + (size_t)src * D;
  float* ar = agg + (size_t)dst * D;
  for (int d = 0; d < D; d++) {
    float a0 = b2[d], a1 = 0, a2 = 0, a3 = 0;
    #pragma unroll
    for (int j = 0; j < 32; j += 4) {
      a0 += t[j]   * w2[d * 32 + j];
      a1 += t[j+1] * w2[d * 32 + j + 1];
      a2 += t[j+2] * w2[d * 32 + j + 2];
      a3 += t[j+3] * w2[d * 32 + j + 3];
    }
    float wm = (a0 + a1) + (a2 + a3);
    atomicAdd(&ar[d], wm * cv * hr[d]);
  }
}

__global__ __launch_bounds__(256) void k_scale(float* __restrict__ agg,
                                               const float* __restrict__ dinv) {
  int i = blockIdx.x * 256 + threadIdx.x;
  if (i < NN * D) agg[i] *= dinv[i >> 6];
}

// ---- Set2Set LSTM ----
__global__ __launch_bounds__(64) void k_lstm(const float* __restrict__ wih,
                                             const float* __restrict__ whh,
                                             const float* __restrict__ bih,
                                             const float* __restrict__ bhh,
                                             float* __restrict__ qstar,
                                             float* __restrict__ hl,
                                             float* __restrict__ cl) {
  int g = blockIdx.x, d = threadIdx.x;
  const float* qs = qstar + g * 2 * D;
  const float* hr = hl + g * D;
  float ai = bih[d]         + bhh[d];
  float af = bih[D + d]     + bhh[D + d];
  float ag = bih[2 * D + d] + bhh[2 * D + d];
  float ao = bih[3 * D + d] + bhh[3 * D + d];
  #pragma unroll 8
  for (int k = 0; k < 2 * D; k++) {
    float q = qs[k];
    ai += q * wih[d * 2 * D + k];
    af += q * wih[(D + d) * 2 * D + k];
    ag += q * wih[(2 * D + d) * 2 * D + k];
    ao += q * wih[(3 * D + d) * 2 * D + k];
  }
  #pragma unroll 8
  for (int k = 0; k < D; k++) {
    float h = hr[k];
    ai += h * whh[d * D + k];
    af += h * whh[(D + d) * D + k];
    ag += h * whh[(2 * D + d) * D + k];
    ao += h * whh[(3 * D + d) * D + k];
  }
  float c = sigm(af) * cl[g * D + d] + sigm(ai) * tanhf(ag);
  float hn = sigm(ao) * tanhf(c);
  cl[g * D + d] = c;
  hl[g * D + d] = hn;
  qstar[g * 2 * D + d] = hn;
}

// ---- Set2Set attention ----
__global__ __launch_bounds__(256) void k_attn(const float* __restrict__ S,
                                              const int* __restrict__ bounds,
                                              float* __restrict__ qstar,
                                              float* __restrict__ ebuf) {
  __shared__ float qv[D];
  __shared__ float red[256];
  int g = blockIdx.x, tid = threadIdx.x;
  int s = bounds[g], en = bounds[g + 1];
  if (tid < D) qv[tid] = qstar[g * 2 * D + tid];
  __syncthreads();
  float lmax = -1e30f;
  for (int n = s + tid; n < en; n += 256) {
    const float4* Sv = (const float4*)(S + (size_t)n * D);
    float a0 = 0, a1 = 0, a2 = 0, a3 = 0;
    #pragma unroll
    for (int q = 0; q < 16; q++) {
      float4 v = Sv[q];
      a0 += v.x * qv[4*q]; a1 += v.y * qv[4*q+1];
      a2 += v.z * qv[4*q+2]; a3 += v.w * qv[4*q+3];
    }
    float e = (a0 + a1) + (a2 + a3);
    ebuf[n] = e;
    lmax = fmaxf(lmax, e);
  }
  red[tid] = lmax; __syncthreads();
  for (int st = 128; st > 0; st >>= 1) {
    if (tid < st) red[tid] = fmaxf(red[tid], red[tid + st]);
    __syncthreads();
  }
  float smax = red[0]; __syncthreads();
  float lsum = 0;
  for (int n = s + tid; n < en; n += 256) {
    float p = expf(ebuf[n] - smax);
    ebuf[n] = p;
    lsum += p;
  }
  red[tid] = lsum; __syncthreads();
  for (int st = 128; st > 0; st >>= 1) {
    if (tid < st) red[tid] += red[tid + st];
    __syncthreads();
  }
  float inv = red[0] > 0.f ? 1.0f / red[0] : 0.0f;
  __syncthreads();
  int grp = tid >> 6, d = tid & 63;
  float acc = 0;
  for (int n = s + grp; n < en; n += 4)
    acc += ebuf[n] * S[(size_t)n * D + d];
  red[tid] = acc; __syncthreads();
  if (tid < D)
    qstar[g * 2 * D + D + tid] =
        (red[tid] + red[64 + tid] + red[128 + tid] + red[192 + tid]) * inv;
}

// ---- final head ----
__global__ __launch_bounds__(64) void k_final(const float* __restrict__ qstar,
                                              const float* __restrict__ w1,
                                              const float* __restrict__ b1,
                                              const float* __restrict__ w2,
                                              const float* __restrict__ b2,
                                              const int* __restrict__ z,
                                              const float* __restrict__ eref,
                                              const float* __restrict__ aref,
                                              const int* __restrict__ bounds,
                                              float* __restrict__ outp) {
  __shared__ float red[D];
  int g = blockIdx.x, d = threadIdx.x;
  const float* qs = qstar + g * 2 * D;
  float a0 = 0, a1 = 0, a2 = 0, a3 = 0;
  #pragma unroll
  for (int k = 0; k < 2 * D; k += 4) {
    a0 += qs[k]   * w1[d * 2 * D + k];
    a1 += qs[k+1] * w1[d * 2 * D + k + 1];
    a2 += qs[k+2] * w1[d * 2 * D + k + 2];
    a3 += qs[k+3] * w1[d * 2 * D + k + 3];
  }
  float gv = fmaxf((a0 + a1) + (a2 + a3) + b1[d], 0.0f);
  red[d] = gv * w2[d];
  __syncthreads();
  for (int st = 32; st > 0; st >>= 1) {
    if (d < st) red[d] += red[d + st];
    __syncthreads();
  }
  float energy = red[0] + b2[0];
  __syncthreads();
  int s = bounds[g], en = bounds[g + 1];
  float racc = 0;
  for (int n = s + d; n < en; n += 64) {
    int zz = z[n];
    racc += eref[zz] + aref[zz];
  }
  red[d] = racc; __syncthreads();
  for (int st = 32; st > 0; st >>= 1) {
    if (d < st) red[d] += red[d + st];
    __syncthreads();
  }
  if (d == 0) outp[g] = energy + red[0];
}

extern "C" void kernel_launch(void* const* d_in, const int* in_sizes, int n_in,
                              void* d_out, int out_size, void* d_ws, size_t ws_size,
                              hipStream_t stream) {
  const float* x      = (const float*)d_in[0];
  const int*   ei     = (const int*)d_in[1];
  const float* ew     = (const float*)d_in[2];
  const float* ea     = (const float*)d_in[3];
  const int*   z      = (const int*)d_in[4];
  const int*   batch  = (const int*)d_in[5];
  const float* lin0_w = (const float*)d_in[6];
  const float* lin0_b = (const float*)d_in[7];
  const float* cw1    = (const float*)d_in[8];
  const float* cb1    = (const float*)d_in[9];
  const float* cw2    = (const float*)d_in[10];
  const float* cb2    = (const float*)d_in[11];
  const float* cl1w   = (const float*)d_in[12];
  const float* cl2w   = (const float*)d_in[13];
  const float* cl2b   = (const float*)d_in[14];
  const float* cl3w   = (const float*)d_in[15];
  const float* cl3b   = (const float*)d_in[16];
  const float* gwih   = (const float*)d_in[17];
  const float* gwhh   = (const float*)d_in[18];
  const float* gbih   = (const float*)d_in[19];
  const float* gbhh   = (const float*)d_in[20];
  const float* lwih   = (const float*)d_in[21];
  const float* lwhh   = (const float*)d_in[22];
  const float* lbih   = (const float*)d_in[23];
  const float* lbhh   = (const float*)d_in[24];
  const float* l1w    = (const float*)d_in[25];
  const float* l1b    = (const float*)d_in[26];
  const float* l2w    = (const float*)d_in[27];
  const float* l2b    = (const float*)d_in[28];
  const float* aref   = (const float*)d_in[29];
  const float* eref   = (const float*)d_in[30];
  float* outp = (float*)d_out;

  const long NND = (long)NN * D;
  float* f = (float*)d_ws;
  long cur = 0;
  long oS0 = cur;   cur += NND;
  long oS1 = cur;   cur += NND;
  long oHX = cur;   cur += NND;
  long oAG = cur;   cur += NND;
  long oCP = cur;   cur += NE;
  long oDI = cur;   cur += 50176;
  long oEB = cur;   cur += 50176;  // ebuf / degi(cursor)
  long oQ  = cur;   cur += NG * 2 * D;
  long oHL = cur;   cur += NG * D;
  long oCL = cur;   cur += NG * D;
  long oW1 = cur;   cur += 8192;
  long oBN = cur;   cur += 256;
  long oES = cur;   cur += NE;
  long oIV = cur;   cur += NE;
  long oSR = cur;   cur += NE;
  long oST = cur;   cur += 51200;
  long oBS = cur;   cur += 256;
  long baseEnd = cur;

  float* S0   = f + oS0;
  float* S1   = f + oS1;
  float* hxb  = f + oHX;
  float* aggb = f + oAG;
  float* Cp   = f + oCP;
  float* dinv = f + oDI;
  float* ebuf = f + oEB;
  int*   degi = (int*)(f + oEB);
  float* qstar= f + oQ;
  float* hl   = f + oHL;
  float* cls  = f + oCL;
  float* w1t  = f + oW1;
  int*   bounds = (int*)(f + oBN);
  int*   es   = (int*)(f + oES);
  int*   inv  = (int*)(f + oIV);
  int*   ssrc = (int*)(f + oSR);
  int*   startA = (int*)(f + oST);
  int*   bsum = (int*)(f + oBS);

  long wsF = (long)(ws_size / 4);
  long rem = wsF - baseEnd;
  long t1f = (long)NE * 32;
  int mode;
  int NCH = 0;
  long capChunk = 0;
  if (t1f <= rem) {
    mode = 2;
  } else {
    mode = 0;
    for (int c = 8; c <= 64; c++) {
      long nper = (NN + c - 1) / c;
      long need = ((long)NE * nper / NN) * 13 / 10 + 4096;
      if (need * D <= rem) { mode = 1; NCH = c; capChunk = need; break; }
    }
  }
  float* T1   = f + baseEnd;   // mode2
  float* msgc = f + baseEnd;   // mode1

  hipMemsetAsync(degi, 0, NN * sizeof(int), stream);
  hipMemsetAsync(qstar, 0, (NG * 2 * D + 2 * NG * D) * sizeof(float), stream);

  k_deg<<<(NE + 255) / 256, 256, 0, stream>>>(ei, degi);
  if (mode) {
    k_scan1<<<NB1, 256, 0, stream>>>(degi, startA, dinv, bsum);
    k_scan2<<<1, 256, 0, stream>>>(bsum);
    k_scan3<<<NB1, 256, 0, stream>>>(startA, bsum);
    k_slot2<<<(NE + 255) / 256, 256, 0, stream>>>(ei, ew, startA, degi, es, inv,
                                                  ssrc, Cp);
  } else {
    k_dinv<<<(NN + 255) / 256, 256, 0, stream>>>(degi, dinv);
    k_envC<<<(NE + 255) / 256, 256, 0, stream>>>(ew, Cp);
  }
  if (mode < 2) k_prep<<<19, 256, 0, stream>>>(cw1, w1t);
  k_lin0q<<<dim3((NN + 255) / 256, 4), 256, 0, stream>>>(x, lin0_w, lin0_b, S0);
  k_bounds<<<1, 192, 0, stream>>>(batch, bounds);

  const int NBK = (NN + 63) / 64;
  // initial hx from S0
  k_stage<0><<<NBK, 256, 0, stream>>>(S0, cl1w, nullptr, hxb);

  for (int b = 0; b < NBLK; b++) {
    float* Sin  = (b & 1) ? S1 : S0;
    float* Sout = (b & 1) ? S0 : S1;
    if (mode == 2) {
      k_mlp1<<<NE / 64, 256, 0, stream>>>(ea, cw1 + b * 32 * EHD, cb1 + b * 32,
                                          inv, T1);
      k_fagg<<<(NN + 3) / 4, 256, 0, stream>>>(T1, cw2 + b * D * 32, cb2 + b * D,
                                               Cp, ssrc, startA, hxb, dinv, aggb);
    } else if (mode == 1) {
      int nodesPer = (NN + NCH - 1) / NCH;
      for (int c = 0; c < NCH; c++) {
        int n0 = c * nodesPer;
        int n1 = n0 + nodesPer; if (n1 > NN) n1 = NN;
        if (n0 >= n1) break;
        k_edgeg<<<(int)((capChunk + 255) / 256), 256, 0, stream>>>(
            ea, w1t + b * EHD * 32, cb1 + b * 32, cw2 + b * D * 32, cb2 + b * D,
            Cp, ssrc, es, startA, hxb, msgc, n0, n1, (int)capChunk);
        k_agg2<<<(n1 - n0 + 3) / 4, 256, 0, stream>>>(msgc, startA, dinv, aggb,
                                                      n0, n1, (int)capChunk);
      }
    } else {
      hipMemsetAsync(aggb, 0, NND * sizeof(float), stream);
      k_edge<<<(NE + 255) / 256, 256, 0, stream>>>(
          ea, w1t + b * EHD * 32, cb1 + b * 32, cw2 + b * D * 32, cb2 + b * D,
          Cp, ei, hxb, aggb);
      k_scale<<<(NN * D + 255) / 256, 256, 0, stream>>>(aggb, dinv);
    }
    const float* w1n = (b + 1 < NBLK) ? (cl1w + (b + 1) * D * D) : nullptr;
    k_nodeblk<<<NBK, 256, 0, stream>>>(aggb, Sin,
                                       cl2w + b * D * D, cl2b + b * D,
                                       cl3w + b * D * D, cl3b + b * D,
                                       gwih, gwhh, gbih, gbhh,
                                       Sout, w1n, hxb);
  }

  float* Sfin = (NBLK & 1) ? S1 : S0;
  for (int it = 0; it < 3; it++) {
    k_lstm<<<NG, 64, 0, stream>>>(lwih, lwhh, lbih, lbhh, qstar, hl, cls);
    k_attn<<<NG, 256, 0, stream>>>(Sfin, bounds, qstar, ebuf);
  }

  k_final<<<NG, 64, 0, stream>>>(qstar, l1w, l1b, l2w, l2b, z, eref, aref,
                                 bounds, outp);
}

// Round 5
// 1258.184 us; speedup vs baseline: 9.2339x; 1.4028x over previous
//
#include <hip/hip_runtime.h>
#include <math.h>

#define NN 50000      // nodes
#define NE 1000000    // edges
#define D 64          // hidden
#define FIN 19
#define EHD 50        // edge attr dim
#define NG 128        // graphs
#define NBLK 3
#define NB1 196       // (NN+255)/256

#define PI_OVER_CUT 0.6283185307179586f
#define LN2F 0.6931471805599453f

static __device__ __forceinline__ float sspf(float x) {
  return fmaxf(x, 0.0f) + log1pf(expf(-fabsf(x))) - LN2F;
}
static __device__ __forceinline__ float sigm(float x) {
  return 1.0f / (1.0f + expf(-x));
}

// ---- degree count ----
__global__ __launch_bounds__(256) void k_deg(const int* __restrict__ ei,
                                             int* __restrict__ degi) {
  int e = blockIdx.x * 256 + threadIdx.x;
  if (e < NE) atomicAdd(&degi[ei[NE + e]], 1);
}

// ---- parallel scan pass 1 ----
__global__ __launch_bounds__(256) void k_scan1(int* __restrict__ degi,
                                               int* __restrict__ start,
                                               float* __restrict__ dinv,
                                               int* __restrict__ bsum) {
  __shared__ int sc[256];
  int t = threadIdx.x;
  int i = blockIdx.x * 256 + t;
  int d = (i < NN) ? degi[i] : 0;
  sc[t] = d; __syncthreads();
  for (int off = 1; off < 256; off <<= 1) {
    int u = (t >= off) ? sc[t - off] : 0;
    __syncthreads();
    sc[t] += u;
    __syncthreads();
  }
  if (i < NN) {
    start[i] = sc[t] - d;
    dinv[i] = 1.0f / fmaxf((float)d, 1.0f);
    degi[i] = 0;                          // becomes cursor for k_slot2
  }
  if (t == 255) bsum[blockIdx.x] = sc[255];
}

// ---- scan pass 2 ----
__global__ __launch_bounds__(256) void k_scan2(int* __restrict__ bsum) {
  __shared__ int sc[256];
  int t = threadIdx.x;
  int v = (t < NB1) ? bsum[t] : 0;
  sc[t] = v; __syncthreads();
  for (int off = 1; off < 256; off <<= 1) {
    int u = (t >= off) ? sc[t - off] : 0;
    __syncthreads();
    sc[t] += u;
    __syncthreads();
  }
  bsum[t] = sc[t] - v;
}

// ---- scan pass 3 ----
__global__ __launch_bounds__(256) void k_scan3(int* __restrict__ start,
                                               const int* __restrict__ bsum) {
  int i = blockIdx.x * 256 + threadIdx.x;
  if (i < NN) start[i] += bsum[blockIdx.x];
  if (i == 0) start[NN] = NE;
}

// ---- CSR slot assignment: es/ssrc/sdst/Cp in slot order ----
__global__ __launch_bounds__(256) void k_slot2(const int* __restrict__ ei,
                                               const float* __restrict__ ew,
                                               const int* __restrict__ start,
                                               int* __restrict__ cursor,
                                               int* __restrict__ es,
                                               int* __restrict__ ssrc,
                                               int* __restrict__ sdst,
                                               float* __restrict__ Cp) {
  int e = blockIdx.x * 256 + threadIdx.x;
  if (e >= NE) return;
  int dst = ei[NE + e];
  int ofs = atomicAdd(&cursor[dst], 1);
  int s = start[dst] + ofs;
  es[s] = e;
  ssrc[s] = ei[e];
  sdst[s] = dst;
  Cp[s] = cosf(ew[e] * PI_OVER_CUT) * 0.5f + 0.5f;
}

// ---- graph boundaries ----
__global__ void k_bounds(const int* __restrict__ batch, int* __restrict__ bounds) {
  int g = threadIdx.x;
  if (g > NG) return;
  int lo = 0, hi = NN;
  while (lo < hi) { int mid = (lo + hi) >> 1; if (batch[mid] < g) lo = mid + 1; else hi = mid; }
  bounds[g] = lo;
}

// ---- lin0 quarter-split ----
__global__ __launch_bounds__(256) void k_lin0q(const float* __restrict__ x,
                                               const float* __restrict__ w,
                                               const float* __restrict__ bias,
                                               float* __restrict__ S) {
  int n = blockIdx.x * 256 + threadIdx.x;
  int q = blockIdx.y;
  if (n >= NN) return;
  float xr[FIN];
  #pragma unroll
  for (int k = 0; k < FIN; k++) xr[k] = x[n * FIN + k];
  #pragma unroll
  for (int i = 0; i < 16; i++) {
    int d = q * 16 + i;
    float a0 = bias[d], a1 = 0.f;
    #pragma unroll
    for (int k = 0; k < FIN - 1; k += 2) {
      a0 += xr[k] * w[d * FIN + k];
      a1 += xr[k + 1] * w[d * FIN + k + 1];
    }
    a0 += xr[FIN - 1] * w[d * FIN + FIN - 1];
    float acc = a0 + a1;
    S[(size_t)n * D + d] = acc > 0.f ? acc : 0.01f * acc;
  }
}

// ---- tiled GEMV stage (initial hx only) ----
template<int ACT>
__global__ __launch_bounds__(256) void k_stage(const float* __restrict__ in,
                                               const float* __restrict__ w,
                                               const float* __restrict__ bias,
                                               float* __restrict__ out) {
  __shared__ float tile[64 * 65];
  int tid = threadIdx.x;
  long nb = (long)blockIdx.x * 64;
  const float4* src = (const float4*)(in + nb * D);
  #pragma unroll
  for (int r = 0; r < 4; r++) {
    int idx = r * 256 + tid;
    int row = idx >> 4, c4 = idx & 15;
    float4 v = src[idx];
    float* dp = &tile[row * 65 + c4 * 4];
    dp[0] = v.x; dp[1] = v.y; dp[2] = v.z; dp[3] = v.w;
  }
  __syncthreads();
  int q = __builtin_amdgcn_readfirstlane(tid >> 6);
  int lane = tid & 63;
  float acc[16];
  const float* wr = w + q * 16 * D;
  #pragma unroll
  for (int i = 0; i < 16; i++) acc[i] = bias ? bias[q * 16 + i] : 0.0f;
  for (int k = 0; k < D; k++) {
    float a = tile[lane * 65 + k];
    #pragma unroll
    for (int i = 0; i < 16; i++) acc[i] += a * wr[i * D + k];
  }
  __syncthreads();
  #pragma unroll
  for (int i = 0; i < 16; i++) {
    float v = acc[i];
    if (ACT == 1) v = sspf(v);
    tile[lane * 65 + q * 16 + i] = v;
  }
  __syncthreads();
  float4* dst = (float4*)(out + nb * D);
  #pragma unroll
  for (int r = 0; r < 4; r++) {
    int idx = r * 256 + tid;
    int row = idx >> 4, c4 = idx & 15;
    if (nb + row < NN) {
      const float* sp = &tile[row * 65 + c4 * 4];
      dst[idx] = make_float4(sp[0], sp[1], sp[2], sp[3]);
    }
  }
}

// ---- fully fused edge conv: thread = CSR slot; one wave = 64 slots ----
// MLP1+MLP2 in registers (s_load weights, 1 inst/MAC); segmented reduce via
// 16x68 LDS tile (wave-synchronous, conflict-free both directions); one
// 16-consecutive-float atomicAdd burst per segment-chunk.
__global__ __launch_bounds__(64) void k_econv(const float* __restrict__ ea,
                                              const float* __restrict__ w1,
                                              const float* __restrict__ b1,
                                              const float* __restrict__ w2,
                                              const float* __restrict__ b2,
                                              const float* __restrict__ Cp,
                                              const int* __restrict__ es,
                                              const int* __restrict__ ssrc,
                                              const int* __restrict__ sdst,
                                              const float* __restrict__ hx,
                                              float* __restrict__ agg) {
  __shared__ float tile[16 * 68];
  int lane = threadIdx.x;
  int s = blockIdx.x * 64 + lane;          // NE % 64 == 0: no tail
  int e = es[s];
  int srcn = ssrc[s];
  int me = sdst[s];
  float cv = Cp[s];
  // within-block segment boundaries (sdst is non-decreasing in slot order)
  int pm = __shfl_up(me, 1);
  bool bound = (lane == 0) || (me != pm);
  unsigned long long segmask = __ballot(bound);   // wave-uniform
  // load ea row: 50 floats, 8B-aligned (200B rows) -> float2
  float arr[EHD];
  const float2* er = (const float2*)(ea + (size_t)e * EHD);
  #pragma unroll
  for (int k2 = 0; k2 < EHD / 2; k2++) {
    float2 v = er[k2];
    arr[2 * k2] = v.x; arr[2 * k2 + 1] = v.y;
  }
  // MLP1: t1 = relu(arr @ w1^T + b1), weights wave-uniform -> s_load
  float t1[32];
  #pragma unroll
  for (int j = 0; j < 32; j++) {
    float a0 = b1[j], a1 = 0.f;
    #pragma unroll
    for (int k = 0; k < EHD; k += 2) {
      a0 += arr[k]     * w1[j * EHD + k];
      a1 += arr[k + 1] * w1[j * EHD + k + 1];
    }
    t1[j] = fmaxf(a0 + a1, 0.0f);
  }
  const float4* hrow = (const float4*)(hx + (size_t)srcn * D);
  int dim = lane >> 2, r = lane & 3;
  #pragma unroll
  for (int c = 0; c < 4; c++) {
    float4 hv[4];
    #pragma unroll
    for (int i = 0; i < 4; i++) hv[i] = hrow[c * 4 + i];
    float mg[16];
    #pragma unroll
    for (int u = 0; u < 16; u++) {
      int d = c * 16 + u;
      float a0 = b2[d], a1 = 0, a2 = 0, a3 = 0;
      #pragma unroll
      for (int j = 0; j < 32; j += 4) {
        a0 += t1[j]     * w2[d * 32 + j];
        a1 += t1[j + 1] * w2[d * 32 + j + 1];
        a2 += t1[j + 2] * w2[d * 32 + j + 2];
        a3 += t1[j + 3] * w2[d * 32 + j + 3];
      }
      float4 h4 = hv[u >> 2];
      float hc = (u & 3) == 0 ? h4.x : (u & 3) == 1 ? h4.y
               : (u & 3) == 2 ? h4.z : h4.w;
      mg[u] = ((a0 + a1) + (a2 + a3)) * cv * hc;
    }
    // column write: tile[u][lane]; banks (4u+lane)%32 -> 2-way (free)
    #pragma unroll
    for (int u = 0; u < 16; u++) tile[u * 68 + lane] = mg[u];
    asm volatile("s_waitcnt lgkmcnt(0)" ::: "memory");
    // wave-synchronous segmented reduce over slots
    unsigned long long mask = segmask;
    while (mask) {
      int l0 = __ffsll((unsigned long long)mask) - 1;
      unsigned long long rest = mask & (mask - 1);
      int l1 = rest ? (__ffsll((unsigned long long)rest) - 1) : 64;
      mask = rest;
      int node = __shfl(me, l0);
      float v = 0.f;
      for (int sl = l0 + r; sl < l1; sl += 4)
        v += tile[dim * 68 + sl];          // banks (4dim+r)%32: 2-way free
      v += __shfl_xor(v, 1);
      v += __shfl_xor(v, 2);
      if (r == 0)
        atomicAdd(&agg[(size_t)node * D + c * 16 + dim], v);
    }
    asm volatile("s_waitcnt lgkmcnt(0)" ::: "memory");
  }
}

// ---- fused node pipeline: (agg*dinv)->lin2+ssp->lin3->GRU->next hx ----
__global__ __launch_bounds__(256) void k_nodeblk(const float* __restrict__ agg,
                                                 const float* __restrict__ dinv,
                                                 const float* __restrict__ hin,
                                                 const float* __restrict__ w2,
                                                 const float* __restrict__ b2,
                                                 const float* __restrict__ w3,
                                                 const float* __restrict__ b3,
                                                 const float* __restrict__ wih,
                                                 const float* __restrict__ whh,
                                                 const float* __restrict__ bih,
                                                 const float* __restrict__ bhh,
                                                 float* __restrict__ hout,
                                                 const float* __restrict__ w1n,
                                                 float* __restrict__ hxout) {
  __shared__ float tA[64 * 65];
  __shared__ float tH[64 * 65];
  int tid = threadIdx.x;
  long nb = (long)blockIdx.x * 64;
  const float4* as = (const float4*)(agg + nb * D);
  const float4* hs = (const float4*)(hin + nb * D);
  #pragma unroll
  for (int r = 0; r < 4; r++) {
    int idx = r * 256 + tid;
    int row = idx >> 4, c4 = idx & 15;
    float dv = dinv[nb + row];
    float4 v = as[idx];
    float* dp = &tA[row * 65 + c4 * 4];
    dp[0] = v.x * dv; dp[1] = v.y * dv; dp[2] = v.z * dv; dp[3] = v.w * dv;
    float4 u = hs[idx];
    float* ep = &tH[row * 65 + c4 * 4];
    ep[0] = u.x; ep[1] = u.y; ep[2] = u.z; ep[3] = u.w;
  }
  __syncthreads();
  int q = __builtin_amdgcn_readfirstlane(tid >> 6);
  int lane = tid & 63;
  // phase 1: v1 = ssp(agg @ w2^T + b2)
  {
    float acc[16];
    const float* wr = w2 + q * 16 * D;
    #pragma unroll
    for (int i = 0; i < 16; i++) acc[i] = b2[q * 16 + i];
    for (int k = 0; k < D; k++) {
      float a = tA[lane * 65 + k];
      #pragma unroll
      for (int i = 0; i < 16; i++) acc[i] += a * wr[i * D + k];
    }
    __syncthreads();
    #pragma unroll
    for (int i = 0; i < 16; i++) tA[lane * 65 + q * 16 + i] = sspf(acc[i]);
    __syncthreads();
  }
  // phase 2: m = v1 @ w3^T + b3
  {
    float acc[16];
    const float* wr = w3 + q * 16 * D;
    #pragma unroll
    for (int i = 0; i < 16; i++) acc[i] = b3[q * 16 + i];
    for (int k = 0; k < D; k++) {
      float a = tA[lane * 65 + k];
      #pragma unroll
      for (int i = 0; i < 16; i++) acc[i] += a * wr[i * D + k];
    }
    __syncthreads();
    #pragma unroll
    for (int i = 0; i < 16; i++) tA[lane * 65 + q * 16 + i] = acc[i];
    __syncthreads();
  }
  // phase 3: GRU
  {
    float ir[16], iz[16], inn[16], hr[16], hz[16], hn[16];
    #pragma unroll
    for (int i = 0; i < 16; i++) {
      int dd = q * 16 + i;
      ir[i] = bih[dd]; iz[i] = bih[D + dd]; inn[i] = bih[2 * D + dd];
      hr[i] = bhh[dd]; hz[i] = bhh[D + dd]; hn[i] = bhh[2 * D + dd];
    }
    const float* wi0 = wih + q * 16 * D;
    const float* wi1 = wih + (D + q * 16) * D;
    const float* wi2 = wih + (2 * D + q * 16) * D;
    const float* wh0 = whh + q * 16 * D;
    const float* wh1 = whh + (D + q * 16) * D;
    const float* wh2 = whh + (2 * D + q * 16) * D;
    for (int k = 0; k < D; k++) {
      float mm = tA[lane * 65 + k];
      float hh = tH[lane * 65 + k];
      #pragma unroll
      for (int i = 0; i < 16; i++) {
        ir[i]  += mm * wi0[i * D + k];
        iz[i]  += mm * wi1[i * D + k];
        inn[i] += mm * wi2[i * D + k];
        hr[i]  += hh * wh0[i * D + k];
        hz[i]  += hh * wh1[i * D + k];
        hn[i]  += hh * wh2[i * D + k];
      }
    }
    __syncthreads();
    #pragma unroll
    for (int i = 0; i < 16; i++) {
      float hold = tH[lane * 65 + q * 16 + i];
      float r = sigm(ir[i] + hr[i]);
      float zg = sigm(iz[i] + hz[i]);
      float nn2 = tanhf(inn[i] + r * hn[i]);
      tA[lane * 65 + q * 16 + i] = (1.0f - zg) * nn2 + zg * hold;
    }
    __syncthreads();
  }
  // store h'
  float4* dst = (float4*)(hout + nb * D);
  #pragma unroll
  for (int r = 0; r < 4; r++) {
    int idx = r * 256 + tid;
    int row = idx >> 4, c4 = idx & 15;
    if (nb + row < NN) {
      const float* sp = &tA[row * 65 + c4 * 4];
      dst[idx] = make_float4(sp[0], sp[1], sp[2], sp[3]);
    }
  }
  // phase 4: next-block hx = h' @ w1n^T
  if (w1n) {
    float acc[16];
    const float* wr = w1n + q * 16 * D;
    #pragma unroll
    for (int i = 0; i < 16; i++) acc[i] = 0.0f;
    for (int k = 0; k < D; k++) {
      float a = tA[lane * 65 + k];
      #pragma unroll
      for (int i = 0; i < 16; i++) acc[i] += a * wr[i * D + k];
    }
    __syncthreads();
    #pragma unroll
    for (int i = 0; i < 16; i++) tH[lane * 65 + q * 16 + i] = acc[i];
    __syncthreads();
    float4* dh = (float4*)(hxout + nb * D);
    #pragma unroll
    for (int r = 0; r < 4; r++) {
      int idx = r * 256 + tid;
      int row = idx >> 4, c4 = idx & 15;
      if (nb + row < NN) {
        const float* sp = &tH[row * 65 + c4 * 4];
        dh[idx] = make_float4(sp[0], sp[1], sp[2], sp[3]);
      }
    }
  }
}

// ---- Set2Set LSTM ----
__global__ __launch_bounds__(64) void k_lstm(const float* __restrict__ wih,
                                             const float* __restrict__ whh,
                                             const float* __restrict__ bih,
                                             const float* __restrict__ bhh,
                                             float* __restrict__ qstar,
                                             float* __restrict__ hl,
                                             float* __restrict__ cl) {
  int g = blockIdx.x, d = threadIdx.x;
  const float* qs = qstar + g * 2 * D;
  const float* hr = hl + g * D;
  float ai = bih[d]         + bhh[d];
  float af = bih[D + d]     + bhh[D + d];
  float ag = bih[2 * D + d] + bhh[2 * D + d];
  float ao = bih[3 * D + d] + bhh[3 * D + d];
  #pragma unroll 8
  for (int k = 0; k < 2 * D; k++) {
    float q = qs[k];
    ai += q * wih[d * 2 * D + k];
    af += q * wih[(D + d) * 2 * D + k];
    ag += q * wih[(2 * D + d) * 2 * D + k];
    ao += q * wih[(3 * D + d) * 2 * D + k];
  }
  #pragma unroll 8
  for (int k = 0; k < D; k++) {
    float h = hr[k];
    ai += h * whh[d * D + k];
    af += h * whh[(D + d) * D + k];
    ag += h * whh[(2 * D + d) * D + k];
    ao += h * whh[(3 * D + d) * D + k];
  }
  float c = sigm(af) * cl[g * D + d] + sigm(ai) * tanhf(ag);
  float hn = sigm(ao) * tanhf(c);
  cl[g * D + d] = c;
  hl[g * D + d] = hn;
  qstar[g * 2 * D + d] = hn;
}

// ---- Set2Set attention ----
__global__ __launch_bounds__(256) void k_attn(const float* __restrict__ S,
                                              const int* __restrict__ bounds,
                                              float* __restrict__ qstar,
                                              float* __restrict__ ebuf) {
  __shared__ float qv[D];
  __shared__ float red[256];
  int g = blockIdx.x, tid = threadIdx.x;
  int s = bounds[g], en = bounds[g + 1];
  if (tid < D) qv[tid] = qstar[g * 2 * D + tid];
  __syncthreads();
  float lmax = -1e30f;
  for (int n = s + tid; n < en; n += 256) {
    const float4* Sv = (const float4*)(S + (size_t)n * D);
    float a0 = 0, a1 = 0, a2 = 0, a3 = 0;
    #pragma unroll
    for (int q = 0; q < 16; q++) {
      float4 v = Sv[q];
      a0 += v.x * qv[4*q]; a1 += v.y * qv[4*q+1];
      a2 += v.z * qv[4*q+2]; a3 += v.w * qv[4*q+3];
    }
    float e = (a0 + a1) + (a2 + a3);
    ebuf[n] = e;
    lmax = fmaxf(lmax, e);
  }
  red[tid] = lmax; __syncthreads();
  for (int st = 128; st > 0; st >>= 1) {
    if (tid < st) red[tid] = fmaxf(red[tid], red[tid + st]);
    __syncthreads();
  }
  float smax = red[0]; __syncthreads();
  float lsum = 0;
  for (int n = s + tid; n < en; n += 256) {
    float p = expf(ebuf[n] - smax);
    ebuf[n] = p;
    lsum += p;
  }
  red[tid] = lsum; __syncthreads();
  for (int st = 128; st > 0; st >>= 1) {
    if (tid < st) red[tid] += red[tid + st];
    __syncthreads();
  }
  float inv = red[0] > 0.f ? 1.0f / red[0] : 0.0f;
  __syncthreads();
  int grp = tid >> 6, d = tid & 63;
  float acc = 0;
  for (int n = s + grp; n < en; n += 4)
    acc += ebuf[n] * S[(size_t)n * D + d];
  red[tid] = acc; __syncthreads();
  if (tid < D)
    qstar[g * 2 * D + D + tid] =
        (red[tid] + red[64 + tid] + red[128 + tid] + red[192 + tid]) * inv;
}

// ---- final head ----
__global__ __launch_bounds__(64) void k_final(const float* __restrict__ qstar,
                                              const float* __restrict__ w1,
                                              const float* __restrict__ b1,
                                              const float* __restrict__ w2,
                                              const float* __restrict__ b2,
                                              const int* __restrict__ z,
                                              const float* __restrict__ eref,
                                              const float* __restrict__ aref,
                                              const int* __restrict__ bounds,
                                              float* __restrict__ outp) {
  __shared__ float red[D];
  int g = blockIdx.x, d = threadIdx.x;
  const float* qs = qstar + g * 2 * D;
  float a0 = 0, a1 = 0, a2 = 0, a3 = 0;
  #pragma unroll
  for (int k = 0; k < 2 * D; k += 4) {
    a0 += qs[k]   * w1[d * 2 * D + k];
    a1 += qs[k+1] * w1[d * 2 * D + k + 1];
    a2 += qs[k+2] * w1[d * 2 * D + k + 2];
    a3 += qs[k+3] * w1[d * 2 * D + k + 3];
  }
  float gv = fmaxf((a0 + a1) + (a2 + a3) + b1[d], 0.0f);
  red[d] = gv * w2[d];
  __syncthreads();
  for (int st = 32; st > 0; st >>= 1) {
    if (d < st) red[d] += red[d + st];
    __syncthreads();
  }
  float energy = red[0] + b2[0];
  __syncthreads();
  int s = bounds[g], en = bounds[g + 1];
  float racc = 0;
  for (int n = s + d; n < en; n += 64) {
    int zz = z[n];
    racc += eref[zz] + aref[zz];
  }
  red[d] = racc; __syncthreads();
  for (int st = 32; st > 0; st >>= 1) {
    if (d < st) red[d] += red[d + st];
    __syncthreads();
  }
  if (d == 0) outp[g] = energy + red[0];
}

extern "C" void kernel_launch(void* const* d_in, const int* in_sizes, int n_in,
                              void* d_out, int out_size, void* d_ws, size_t ws_size,
                              hipStream_t stream) {
  const float* x      = (const float*)d_in[0];
  const int*   ei     = (const int*)d_in[1];
  const float* ew     = (const float*)d_in[2];
  const float* ea     = (const float*)d_in[3];
  const int*   z      = (const int*)d_in[4];
  const int*   batch  = (const int*)d_in[5];
  const float* lin0_w = (const float*)d_in[6];
  const float* lin0_b = (const float*)d_in[7];
  const float* cw1    = (const float*)d_in[8];
  const float* cb1    = (const float*)d_in[9];
  const float* cw2    = (const float*)d_in[10];
  const float* cb2    = (const float*)d_in[11];
  const float* cl1w   = (const float*)d_in[12];
  const float* cl2w   = (const float*)d_in[13];
  const float* cl2b   = (const float*)d_in[14];
  const float* cl3w   = (const float*)d_in[15];
  const float* cl3b   = (const float*)d_in[16];
  const float* gwih   = (const float*)d_in[17];
  const float* gwhh   = (const float*)d_in[18];
  const float* gbih   = (const float*)d_in[19];
  const float* gbhh   = (const float*)d_in[20];
  const float* lwih   = (const float*)d_in[21];
  const float* lwhh   = (const float*)d_in[22];
  const float* lbih   = (const float*)d_in[23];
  const float* lbhh   = (const float*)d_in[24];
  const float* l1w    = (const float*)d_in[25];
  const float* l1b    = (const float*)d_in[26];
  const float* l2w    = (const float*)d_in[27];
  const float* l2b    = (const float*)d_in[28];
  const float* aref   = (const float*)d_in[29];
  const float* eref   = (const float*)d_in[30];
  float* outp = (float*)d_out;

  const long NND = (long)NN * D;
  float* f = (float*)d_ws;
  long cur = 0;
  long oS0 = cur;   cur += NND;
  long oS1 = cur;   cur += NND;
  long oHX = cur;   cur += NND;
  long oAG = cur;   cur += NND;
  long oCP = cur;   cur += NE;
  long oDI = cur;   cur += 50176;
  long oEB = cur;   cur += 50176;  // ebuf / degi(cursor)
  long oQ  = cur;   cur += NG * 2 * D;
  long oHL = cur;   cur += NG * D;
  long oCL = cur;   cur += NG * D;
  long oBN = cur;   cur += 256;
  long oES = cur;   cur += NE;
  long oSR = cur;   cur += NE;
  long oSD = cur;   cur += NE;
  long oST = cur;   cur += 51200;
  long oBS = cur;   cur += 256;

  float* S0   = f + oS0;
  float* S1   = f + oS1;
  float* hxb  = f + oHX;
  float* aggb = f + oAG;
  float* Cp   = f + oCP;
  float* dinv = f + oDI;
  float* ebuf = f + oEB;
  int*   degi = (int*)(f + oEB);
  float* qstar= f + oQ;
  float* hl   = f + oHL;
  float* cls  = f + oCL;
  int*   bounds = (int*)(f + oBN);
  int*   es   = (int*)(f + oES);
  int*   ssrc = (int*)(f + oSR);
  int*   sdst = (int*)(f + oSD);
  int*   startA = (int*)(f + oST);
  int*   bsum = (int*)(f + oBS);

  hipMemsetAsync(degi, 0, NN * sizeof(int), stream);
  hipMemsetAsync(qstar, 0, (NG * 2 * D + 2 * NG * D) * sizeof(float), stream);

  k_deg<<<(NE + 255) / 256, 256, 0, stream>>>(ei, degi);
  k_scan1<<<NB1, 256, 0, stream>>>(degi, startA, dinv, bsum);
  k_scan2<<<1, 256, 0, stream>>>(bsum);
  k_scan3<<<NB1, 256, 0, stream>>>(startA, bsum);
  k_slot2<<<(NE + 255) / 256, 256, 0, stream>>>(ei, ew, startA, degi, es, ssrc,
                                                sdst, Cp);
  k_lin0q<<<dim3((NN + 255) / 256, 4), 256, 0, stream>>>(x, lin0_w, lin0_b, S0);
  k_bounds<<<1, 192, 0, stream>>>(batch, bounds);

  const int NBK = (NN + 63) / 64;
  k_stage<0><<<NBK, 256, 0, stream>>>(S0, cl1w, nullptr, hxb);

  for (int b = 0; b < NBLK; b++) {
    float* Sin  = (b & 1) ? S1 : S0;
    float* Sout = (b & 1) ? S0 : S1;
    hipMemsetAsync(aggb, 0, NND * sizeof(float), stream);
    k_econv<<<NE / 64, 64, 0, stream>>>(ea, cw1 + b * 32 * EHD, cb1 + b * 32,
                                        cw2 + b * D * 32, cb2 + b * D,
                                        Cp, es, ssrc, sdst, hxb, aggb);
    const float* w1n = (b + 1 < NBLK) ? (cl1w + (b + 1) * D * D) : nullptr;
    k_nodeblk<<<NBK, 256, 0, stream>>>(aggb, dinv, Sin,
                                       cl2w + b * D * D, cl2b + b * D,
                                       cl3w + b * D * D, cl3b + b * D,
                                       gwih, gwhh, gbih, gbhh,
                                       Sout, w1n, hxb);
  }

  float* Sfin = (NBLK & 1) ? S1 : S0;
  for (int it = 0; it < 3; it++) {
    k_lstm<<<NG, 64, 0, stream>>>(lwih, lwhh, lbih, lbhh, qstar, hl, cls);
    k_attn<<<NG, 256, 0, stream>>>(Sfin, bounds, qstar, ebuf);
  }

  k_final<<<NG, 64, 0, stream>>>(qstar, l1w, l1b, l2w, l2b, z, eref, aref,
                                 bounds, outp);
}